// Round 3
// baseline (167.714 us; speedup 1.0000x reference)
//
#include <hip/hip_runtime.h>

// Anti-causal attention (key s valid iff s > l), scale=1/8 after masking.
// Row L-1 fully masked -> softmax uniform -> out = mean(V) (separate kernels).
// B=2, L=S=2048, H=16, E=D=64, fp32 in/out, bf16 MFMA compute.
// v3: pre-converted bf16 K (head-major) + pre-transposed bf16 V^T in d_ws,
//     LDS-free attention (L2-resident KV), exp2 softmax with defer-max.

#define B_ 2
#define L_ 2048
#define H_ 16
#define E_ 64
#define S_ 2048
#define D_ 64
#define QSCALE 0.18033688011112042f  /* 0.125 * log2(e) */

typedef __attribute__((ext_vector_type(4))) float f32x4;
typedef __attribute__((ext_vector_type(8))) short short8;
typedef __attribute__((ext_vector_type(4))) unsigned int uint4v;

__device__ __forceinline__ unsigned short f2bf(float f) {
  unsigned int u = __builtin_bit_cast(unsigned int, f);
  u = (u + 0x7FFFu + ((u >> 16) & 1u)) >> 16;  // RNE
  return (unsigned short)u;
}
__device__ __forceinline__ unsigned int pkbf(float a, float b) {
  return (unsigned int)f2bf(a) | ((unsigned int)f2bf(b) << 16);
}

// ---------------- prep: K [b][s][h][e] f32 -> Kb [b*h][s][e] bf16 ----------------
__global__ __launch_bounds__(256) void prep_k(const float* __restrict__ Kg,
                                              unsigned short* __restrict__ Kb) {
  const int t = blockIdx.x * 256 + (int)threadIdx.x;  // 524288 threads
  const int orow = t >> 3, e0 = (t & 7) << 3;
  const int s = orow & (S_ - 1), bh = orow >> 11;
  const int b = bh >> 4, h = bh & 15;
  const float* src = Kg + ((size_t)((b * S_ + s) * H_ + h)) * E_ + e0;
  f32x4 a = ((const f32x4*)src)[0], c = ((const f32x4*)src)[1];
  short8 o;
  o[0]=(short)f2bf(a[0]); o[1]=(short)f2bf(a[1]); o[2]=(short)f2bf(a[2]); o[3]=(short)f2bf(a[3]);
  o[4]=(short)f2bf(c[0]); o[5]=(short)f2bf(c[1]); o[6]=(short)f2bf(c[2]); o[7]=(short)f2bf(c[3]);
  *(short8*)(Kb + (size_t)orow * E_ + e0) = o;
}

// ---------------- prep: V [b][s][h][d] f32 -> Vt [b*h][d][s] bf16 ----------------
__global__ __launch_bounds__(256) void prep_vt(const float* __restrict__ Vg,
                                               unsigned short* __restrict__ Vt) {
  const int bh = blockIdx.x & 31, st = blockIdx.x >> 5;  // 32 s-tiles of 64
  const int b = bh >> 4, h = bh & 15;
  const int s0 = st << 6;
  const int tid = (int)threadIdx.x;
  __shared__ unsigned short Tl[64][72];
  {
    const int sr = tid >> 2, d0 = (tid & 3) << 4;
    const float* src = Vg + ((size_t)((b * S_ + s0 + sr) * H_ + h)) * D_ + d0;
    f32x4 v0 = ((const f32x4*)src)[0], v1 = ((const f32x4*)src)[1];
    f32x4 v2 = ((const f32x4*)src)[2], v3 = ((const f32x4*)src)[3];
    unsigned short* dst = &Tl[sr][d0];
    dst[0]=f2bf(v0[0]); dst[1]=f2bf(v0[1]); dst[2]=f2bf(v0[2]); dst[3]=f2bf(v0[3]);
    dst[4]=f2bf(v1[0]); dst[5]=f2bf(v1[1]); dst[6]=f2bf(v1[2]); dst[7]=f2bf(v1[3]);
    dst[8]=f2bf(v2[0]); dst[9]=f2bf(v2[1]); dst[10]=f2bf(v2[2]); dst[11]=f2bf(v2[3]);
    dst[12]=f2bf(v3[0]); dst[13]=f2bf(v3[1]); dst[14]=f2bf(v3[2]); dst[15]=f2bf(v3[3]);
  }
  __syncthreads();
  {
    const int d = tid >> 2, sb = (tid & 3) << 4;
    short8 o0, o1;
#pragma unroll
    for (int j = 0; j < 8; ++j) {
      o0[j] = (short)Tl[sb + j][d];
      o1[j] = (short)Tl[sb + 8 + j][d];
    }
    unsigned short* dst = Vt + ((size_t)bh * D_ + d) * S_ + s0 + sb;
    *(short8*)dst = o0;
    *(short8*)(dst + 8) = o1;
  }
}

// ---------------- main attention (LDS-free, bf16 operands) ----------------
template <bool FIRST>
__device__ __forceinline__ void do_chunk(
    int s0, int lrow, int gp, int c,
    const unsigned short* __restrict__ Kbh, const unsigned short* __restrict__ Vbh,
    const short8& qf0, const short8& qf1,
    f32x4 accO[4], float& m_run, float& dsum) {
  const unsigned short* kr0 = Kbh + (size_t)(s0 + c) * E_ + (gp << 3);
  const unsigned short* kr1 = Kbh + (size_t)(s0 + 16 + c) * E_ + (gp << 3);
  short8 kf00 = *(const short8*)kr0;
  short8 kf01 = *(const short8*)(kr0 + 32);
  short8 kf10 = *(const short8*)kr1;
  short8 kf11 = *(const short8*)(kr1 + 32);
  f32x4 st0 = {0.f, 0.f, 0.f, 0.f}, st1 = {0.f, 0.f, 0.f, 0.f};
  st0 = __builtin_amdgcn_mfma_f32_16x16x32_bf16(kf00, qf0, st0, 0, 0, 0);
  st0 = __builtin_amdgcn_mfma_f32_16x16x32_bf16(kf01, qf1, st0, 0, 0, 0);
  st1 = __builtin_amdgcn_mfma_f32_16x16x32_bf16(kf10, qf0, st1, 0, 0, 0);
  st1 = __builtin_amdgcn_mfma_f32_16x16x32_bf16(kf11, qf1, st1, 0, 0, 0);
  float sarr[8] = {st0[0], st0[1], st0[2], st0[3], st1[0], st1[1], st1[2], st1[3]};

  if (FIRST) {
    // mask (only the first chunk of each wave is partial), then exact row max
#pragma unroll
    for (int i = 0; i < 8; ++i) {
      int sg = s0 + ((i >> 2) << 4) + (gp << 2) + (i & 3);
      if (sg <= lrow) sarr[i] = -1e30f;
    }
    float mx = fmaxf(fmaxf(fmaxf(sarr[0], sarr[1]), fmaxf(sarr[2], sarr[3])),
                     fmaxf(fmaxf(sarr[4], sarr[5]), fmaxf(sarr[6], sarr[7])));
    mx = fmaxf(mx, __shfl_xor(mx, 16));
    mx = fmaxf(mx, __shfl_xor(mx, 32));
    m_run = mx;
  } else {
    float pmax = fmaxf(fmaxf(fmaxf(sarr[0], sarr[1]), fmaxf(sarr[2], sarr[3])),
                       fmaxf(fmaxf(sarr[4], sarr[5]), fmaxf(sarr[6], sarr[7])));
    if (__any(pmax > m_run + 8.0f)) {  // defer-max (T13): rescale rarely
      float rm = fmaxf(pmax, __shfl_xor(pmax, 16));
      rm = fmaxf(rm, __shfl_xor(rm, 32));
      float m_new = fmaxf(m_run, rm);
      float alpha = exp2f(m_run - m_new);
      dsum *= alpha;
      float ar0 = __shfl(alpha, (gp << 2) + 0);
      float ar1 = __shfl(alpha, (gp << 2) + 1);
      float ar2 = __shfl(alpha, (gp << 2) + 2);
      float ar3 = __shfl(alpha, (gp << 2) + 3);
#pragma unroll
      for (int k0 = 0; k0 < 4; ++k0) {
        accO[k0][0] *= ar0; accO[k0][1] *= ar1;
        accO[k0][2] *= ar2; accO[k0][3] *= ar3;
      }
      m_run = m_new;
    }
  }

  float p[8], s8 = 0.f;
#pragma unroll
  for (int i = 0; i < 8; ++i) { p[i] = exp2f(sarr[i] - m_run); s8 += p[i]; }
  dsum += s8;

  // P-fragment redistribution (verified lane mapping from v2)
  unsigned int pA0 = pkbf(p[0], p[1]), pA1 = pkbf(p[2], p[3]);
  unsigned int pB0 = pkbf(p[4], p[5]), pB1 = pkbf(p[6], p[7]);
  const int al = (gp << 1) & 3;
  const int src0 = (al << 4) + c, src1 = src0 + 16;
  unsigned int a0 = (unsigned int)__shfl((int)pA0, src0);
  unsigned int a1 = (unsigned int)__shfl((int)pA1, src0);
  unsigned int a2 = (unsigned int)__shfl((int)pA0, src1);
  unsigned int a3 = (unsigned int)__shfl((int)pA1, src1);
  unsigned int b0 = (unsigned int)__shfl((int)pB0, src0);
  unsigned int b1 = (unsigned int)__shfl((int)pB1, src0);
  unsigned int b2 = (unsigned int)__shfl((int)pB0, src1);
  unsigned int b3 = (unsigned int)__shfl((int)pB1, src1);
  const bool useA = (gp < 2);
  uint4v fv;
  fv[0] = useA ? a0 : b0;
  fv[1] = useA ? a1 : b1;
  fv[2] = useA ? a2 : b2;
  fv[3] = useA ? a3 : b3;
  short8 pf = __builtin_bit_cast(short8, fv);
#pragma unroll
  for (int k0 = 0; k0 < 4; ++k0) {
    short8 vf = *(const short8*)(Vbh + (size_t)((k0 << 4) + c) * S_ + s0 + (gp << 3));
    accO[k0] = __builtin_amdgcn_mfma_f32_16x16x32_bf16(pf, vf, accO[k0], 0, 0, 0);
  }
}

__global__ __launch_bounds__(256) void attn_fwd3(
    const float* __restrict__ Qg, const unsigned short* __restrict__ Kb,
    const unsigned short* __restrict__ Vt, float* __restrict__ Og) {
  const int bh = blockIdx.x;
  const int b = bh >> 4, h = bh & 15;
  const int q0 = blockIdx.y << 6;
  const int tid = (int)threadIdx.x;
  const int lane = tid & 63, w = tid >> 6;
  const int gp = lane >> 4, c = lane & 15;
  const int qbase = q0 + (w << 4);
  const unsigned short* Kbh = Kb + (size_t)bh * (S_ * E_);
  const unsigned short* Vbh = Vt + (size_t)bh * (D_ * S_);

  // Q fragment (scaled by 1/8 * log2(e)), from fp32 global (read once)
  short8 qf0, qf1;
  {
    const float* qrow = Qg + ((size_t)((b * L_ + (qbase + c)) * H_ + h)) * E_;
    const f32x4* q0p = (const f32x4*)(qrow + (gp << 3));
    const f32x4* q1p = (const f32x4*)(qrow + 32 + (gp << 3));
    f32x4 a0 = q0p[0], b0 = q0p[1], a1 = q1p[0], b1 = q1p[1];
    float t0[8] = {a0[0],a0[1],a0[2],a0[3],b0[0],b0[1],b0[2],b0[3]};
    float t1[8] = {a1[0],a1[1],a1[2],a1[3],b1[0],b1[1],b1[2],b1[3]};
#pragma unroll
    for (int j = 0; j < 8; ++j) {
      qf0[j] = (short)f2bf(QSCALE * t0[j]);
      qf1[j] = (short)f2bf(QSCALE * t1[j]);
    }
  }

  f32x4 accO[4];
#pragma unroll
  for (int k0 = 0; k0 < 4; ++k0) accO[k0] = (f32x4){0.f, 0.f, 0.f, 0.f};
  float m_run = -1e30f, dsum = 0.f;
  const int lrow = qbase + c;

  const int ch0 = (qbase + 1) >> 5;  // this wave's first (partial) chunk
  do_chunk<true>(ch0 << 5, lrow, gp, c, Kbh, Vbh, qf0, qf1, accO, m_run, dsum);
  for (int ch = ch0 + 1; ch < (S_ >> 5); ++ch)
    do_chunk<false>(ch << 5, lrow, gp, c, Kbh, Vbh, qf0, qf1, accO, m_run, dsum);

  // reduce per-lane partial denominators across gp groups (once)
  float denom = dsum;
  denom += __shfl_xor(denom, 16);
  denom += __shfl_xor(denom, 32);

  float dr[4];
  dr[0] = __shfl(denom, (gp << 2) + 0);
  dr[1] = __shfl(denom, (gp << 2) + 1);
  dr[2] = __shfl(denom, (gp << 2) + 2);
  dr[3] = __shfl(denom, (gp << 2) + 3);
#pragma unroll
  for (int r = 0; r < 4; ++r) {
    const int grow = qbase + (gp << 2) + r;
    if (grow == L_ - 1) continue;  // fully-masked row: vmean kernels own it
    const size_t base = ((size_t)((b * L_ + grow) * H_ + h)) * D_ + c;
    const float inv = 1.0f / dr[r];
    Og[base +  0] = accO[0][r] * inv;
    Og[base + 16] = accO[1][r] * inv;
    Og[base + 32] = accO[2][r] * inv;
    Og[base + 48] = accO[3][r] * inv;
  }
}

// ---------------- row L-1 fixup: mean(V) two-stage ----------------
__global__ __launch_bounds__(256) void vmean_part(const float* __restrict__ Vg,
                                                  float* __restrict__ ws) {
  const int g = blockIdx.x;
  const int slab = g & 15, bh = g >> 4;
  const int b = bh >> 4, h = bh & 15;
  const int lane = (int)threadIdx.x & 63, w = (int)threadIdx.x >> 6;
  const int s0 = (slab << 7) + (w << 5);
  const float* base = Vg + ((size_t)((b * S_ + s0) * H_ + h)) * D_ + lane;
  float sum = 0.f;
#pragma unroll 4
  for (int i = 0; i < 32; ++i) sum += base[(size_t)i * (H_ * D_)];
  __shared__ float red[4][64];
  red[w][lane] = sum;
  __syncthreads();
  if (w == 0)
    ws[(size_t)g * 64 + lane] =
        red[0][lane] + red[1][lane] + red[2][lane] + red[3][lane];
}

__global__ __launch_bounds__(64) void vmean_comb(const float* __restrict__ ws,
                                                 float* __restrict__ Og) {
  const int bh = blockIdx.x;
  const int b = bh >> 4, h = bh & 15;
  const int lane = (int)threadIdx.x;
  float t = 0.f;
#pragma unroll
  for (int i = 0; i < 16; ++i) t += ws[(size_t)(bh * 16 + i) * 64 + lane];
  Og[((size_t)((b * L_ + (L_ - 1)) * H_ + h)) * D_ + lane] = t * (1.0f / (float)S_);
}

// ---------------- fallback path (v2, LDS-staged) if ws too small ----------------
__global__ __launch_bounds__(256) void attn_fwd(
    const float* __restrict__ Qg, const float* __restrict__ Kg,
    const float* __restrict__ Vg, float* __restrict__ Og) {
  const int bh = blockIdx.x;
  const int b = bh >> 4, h = bh & 15;
  const int q0 = blockIdx.y << 6;
  const int tid = (int)threadIdx.x;
  const int lane = tid & 63;
  const int w = tid >> 6;
  const int gp = lane >> 4;
  const int c = lane & 15;
  const int qbase = q0 + (w << 4);

  __shared__ unsigned short Kl[32][72];
  __shared__ unsigned short Vts[64][40];

  short8 qf0, qf1;
  {
    const float* qrow = Qg + ((size_t)((b * L_ + (qbase + c)) * H_ + h)) * E_;
    const f32x4* q0p = (const f32x4*)(qrow + (gp << 3));
    const f32x4* q1p = (const f32x4*)(qrow + 32 + (gp << 3));
    f32x4 a0 = q0p[0], b0 = q0p[1], a1 = q1p[0], b1 = q1p[1];
    float t0[8] = {a0[0],a0[1],a0[2],a0[3],b0[0],b0[1],b0[2],b0[3]};
    float t1[8] = {a1[0],a1[1],a1[2],a1[3],b1[0],b1[1],b1[2],b1[3]};
#pragma unroll
    for (int j = 0; j < 8; ++j) {
      qf0[j] = (short)f2bf(0.125f * t0[j]);
      qf1[j] = (short)f2bf(0.125f * t1[j]);
    }
  }

  f32x4 accO[4];
#pragma unroll
  for (int k0 = 0; k0 < 4; ++k0) accO[k0] = (f32x4){0.f, 0.f, 0.f, 0.f};
  float m_run = -1e30f, denom = 0.f;

  const int c0 = (q0 + 1) >> 5;
  const int srow = tid >> 3;
  const int scol = (tid & 7) << 3;

  for (int ch = c0; ch < (S_ >> 5); ++ch) {
    const int s0 = ch << 5;
    __syncthreads();
    {
      const size_t rbase = ((size_t)((b * S_ + (s0 + srow)) * H_ + h));
      const float* kp = Kg + rbase * E_ + scol;
      f32x4 ka = *(const f32x4*)kp;
      f32x4 kb = *(const f32x4*)(kp + 4);
      short8 kv;
      kv[0]=(short)f2bf(ka[0]); kv[1]=(short)f2bf(ka[1]);
      kv[2]=(short)f2bf(ka[2]); kv[3]=(short)f2bf(ka[3]);
      kv[4]=(short)f2bf(kb[0]); kv[5]=(short)f2bf(kb[1]);
      kv[6]=(short)f2bf(kb[2]); kv[7]=(short)f2bf(kb[3]);
      *(short8*)&Kl[srow][scol] = kv;
      const float* vp = Vg + rbase * D_ + scol;
      f32x4 va = *(const f32x4*)vp;
      f32x4 vb = *(const f32x4*)(vp + 4);
      Vts[scol + 0][srow] = f2bf(va[0]);
      Vts[scol + 1][srow] = f2bf(va[1]);
      Vts[scol + 2][srow] = f2bf(va[2]);
      Vts[scol + 3][srow] = f2bf(va[3]);
      Vts[scol + 4][srow] = f2bf(vb[0]);
      Vts[scol + 5][srow] = f2bf(vb[1]);
      Vts[scol + 6][srow] = f2bf(vb[2]);
      Vts[scol + 7][srow] = f2bf(vb[3]);
    }
    __syncthreads();
    if (s0 + 31 <= qbase) continue;

    f32x4 st0 = {0.f,0.f,0.f,0.f}, st1 = {0.f,0.f,0.f,0.f};
    {
      short8 kf;
      kf = *(const short8*)&Kl[c][(gp << 3)];
      st0 = __builtin_amdgcn_mfma_f32_16x16x32_bf16(kf, qf0, st0, 0, 0, 0);
      kf = *(const short8*)&Kl[c][32 + (gp << 3)];
      st0 = __builtin_amdgcn_mfma_f32_16x16x32_bf16(kf, qf1, st0, 0, 0, 0);
      kf = *(const short8*)&Kl[16 + c][(gp << 3)];
      st1 = __builtin_amdgcn_mfma_f32_16x16x32_bf16(kf, qf0, st1, 0, 0, 0);
      kf = *(const short8*)&Kl[16 + c][32 + (gp << 3)];
      st1 = __builtin_amdgcn_mfma_f32_16x16x32_bf16(kf, qf1, st1, 0, 0, 0);
    }

    const int lrow = qbase + c;
    float p[8];
    {
      float sarr[8] = {st0[0], st0[1], st0[2], st0[3], st1[0], st1[1], st1[2], st1[3]};
      float mx = -1e30f;
#pragma unroll
      for (int i = 0; i < 8; ++i) {
        int sg = s0 + ((i >> 2) << 4) + (gp << 2) + (i & 3);
        float v = (sg > lrow) ? sarr[i] : -1e30f;
        p[i] = v;
        mx = fmaxf(mx, v);
      }
      mx = fmaxf(mx, __shfl_xor(mx, 16));
      mx = fmaxf(mx, __shfl_xor(mx, 32));
      float m_new = fmaxf(m_run, mx);
      float sum = 0.f;
#pragma unroll
      for (int i = 0; i < 8; ++i) { p[i] = __expf(p[i] - m_new); sum += p[i]; }
      sum += __shfl_xor(sum, 16);
      sum += __shfl_xor(sum, 32);
      float alpha = __expf(m_run - m_new);
      m_run = m_new;
      denom = denom * alpha + sum;
      float ar0 = __shfl(alpha, (gp << 2) + 0);
      float ar1 = __shfl(alpha, (gp << 2) + 1);
      float ar2 = __shfl(alpha, (gp << 2) + 2);
      float ar3 = __shfl(alpha, (gp << 2) + 3);
#pragma unroll
      for (int k0 = 0; k0 < 4; ++k0) {
        accO[k0][0] *= ar0; accO[k0][1] *= ar1;
        accO[k0][2] *= ar2; accO[k0][3] *= ar3;
      }
    }

    {
      unsigned int pA0 = pkbf(p[0], p[1]), pA1 = pkbf(p[2], p[3]);
      unsigned int pB0 = pkbf(p[4], p[5]), pB1 = pkbf(p[6], p[7]);
      const int al = (gp << 1) & 3;
      const int src0 = (al << 4) + c, src1 = src0 + 16;
      unsigned int a0 = (unsigned int)__shfl((int)pA0, src0);
      unsigned int a1 = (unsigned int)__shfl((int)pA1, src0);
      unsigned int a2 = (unsigned int)__shfl((int)pA0, src1);
      unsigned int a3 = (unsigned int)__shfl((int)pA1, src1);
      unsigned int b0 = (unsigned int)__shfl((int)pB0, src0);
      unsigned int b1 = (unsigned int)__shfl((int)pB1, src0);
      unsigned int b2 = (unsigned int)__shfl((int)pB0, src1);
      unsigned int b3 = (unsigned int)__shfl((int)pB1, src1);
      const bool useA = (gp < 2);
      uint4v fv;
      fv[0] = useA ? a0 : b0;
      fv[1] = useA ? a1 : b1;
      fv[2] = useA ? a2 : b2;
      fv[3] = useA ? a3 : b3;
      short8 pf = __builtin_bit_cast(short8, fv);
#pragma unroll
      for (int k0 = 0; k0 < 4; ++k0) {
        short8 vf = *(const short8*)&Vts[(k0 << 4) + c][(gp << 3)];
        accO[k0] = __builtin_amdgcn_mfma_f32_16x16x32_bf16(pf, vf, accO[k0], 0, 0, 0);
      }
    }
  }

  float dr[4];
  dr[0] = __shfl(denom, (gp << 2) + 0);
  dr[1] = __shfl(denom, (gp << 2) + 1);
  dr[2] = __shfl(denom, (gp << 2) + 2);
  dr[3] = __shfl(denom, (gp << 2) + 3);
#pragma unroll
  for (int r = 0; r < 4; ++r) {
    const int grow = qbase + (gp << 2) + r;
    if (grow == L_ - 1) continue;
    const size_t base = ((size_t)((b * L_ + grow) * H_ + h)) * D_ + c;
    const float inv = 1.0f / dr[r];
    Og[base +  0] = accO[0][r] * inv;
    Og[base + 16] = accO[1][r] * inv;
    Og[base + 32] = accO[2][r] * inv;
    Og[base + 48] = accO[3][r] * inv;
  }
}

__global__ __launch_bounds__(256) void vmean_fix(const float* __restrict__ Vg,
                                                 float* __restrict__ Og) {
  const int bh = blockIdx.x;
  const int b = bh >> 4, h = bh & 15;
  const int t = (int)threadIdx.x;
  const int lane = t & 63, w = t >> 6;
  float sum = 0.f;
  for (int s = w; s < S_; s += 4)
    sum += Vg[((size_t)((b * S_ + s) * H_ + h)) * D_ + lane];
  __shared__ float red[4][64];
  red[w][lane] = sum;
  __syncthreads();
  if (w == 0) {
    float tot = red[0][lane] + red[1][lane] + red[2][lane] + red[3][lane];
    Og[((size_t)((b * L_ + (L_ - 1)) * H_ + h)) * D_ + lane] = tot * (1.0f / (float)S_);
  }
}

extern "C" void kernel_launch(void* const* d_in, const int* in_sizes, int n_in,
                              void* d_out, int out_size, void* d_ws, size_t ws_size,
                              hipStream_t stream) {
  const float* Q = (const float*)d_in[0];
  const float* K = (const float*)d_in[1];
  const float* V = (const float*)d_in[2];
  float* O = (float*)d_out;
  const size_t szK = (size_t)B_ * H_ * S_ * E_ * 2;    // 8 MB
  const size_t szV = (size_t)B_ * H_ * D_ * S_ * 2;    // 8 MB
  const size_t szP = (size_t)(B_ * H_ * 16) * 64 * 4;  // 128 KB

  if (ws_size >= szK + szV + szP) {
    unsigned short* Kb = (unsigned short*)d_ws;
    unsigned short* Vt = (unsigned short*)((char*)d_ws + szK);
    float* part = (float*)((char*)d_ws + szK + szV);
    prep_k<<<dim3((B_ * H_ * S_ * 8) / 256), dim3(256), 0, stream>>>(K, Kb);
    prep_vt<<<dim3(B_ * H_ * (S_ / 64)), dim3(256), 0, stream>>>(V, Vt);
    attn_fwd3<<<dim3(B_ * H_, L_ / 64), dim3(256), 0, stream>>>(Q, Kb, Vt, O);
    vmean_part<<<dim3(B_ * H_ * 16), dim3(256), 0, stream>>>(V, part);
    vmean_comb<<<dim3(B_ * H_), dim3(64), 0, stream>>>(part, O);
  } else if (ws_size >= szP) {
    float* part = (float*)d_ws;
    attn_fwd<<<dim3(B_ * H_, L_ / 64), dim3(256), 0, stream>>>(Q, K, V, O);
    vmean_part<<<dim3(B_ * H_ * 16), dim3(256), 0, stream>>>(V, part);
    vmean_comb<<<dim3(B_ * H_), dim3(64), 0, stream>>>(part, O);
  } else {
    attn_fwd<<<dim3(B_ * H_, L_ / 64), dim3(256), 0, stream>>>(Q, K, V, O);
    vmean_fix<<<dim3(B_ * H_), dim3(256), 0, stream>>>(V, O);
  }
}

// Round 5
// 154.811 us; speedup vs baseline: 1.0833x; 1.0833x over previous
//
#include <hip/hip_runtime.h>

// Anti-causal attention (key s valid iff s > l), scale=1/8 after masking.
// Row L-1 fully masked -> softmax uniform -> out = mean(V) (separate kernels).
// B=2, L=S=2048, H=16, E=D=64, fp32 in/out, bf16 MFMA compute.
// v4b: LDS-free + register ping-pong prefetch (hide K/V load latency under
//      compute), software RNE bf16 pack, exp2 softmax with defer-max.

#define B_ 2
#define L_ 2048
#define H_ 16
#define E_ 64
#define S_ 2048
#define D_ 64
#define QSCALE 0.18033688011112042f  /* 0.125 * log2(e) */

typedef __attribute__((ext_vector_type(4))) float f32x4;
typedef __attribute__((ext_vector_type(8))) short short8;
typedef __attribute__((ext_vector_type(4))) unsigned int uint4v;

__device__ __forceinline__ unsigned short f2bf(float f) {
  unsigned int u = __builtin_bit_cast(unsigned int, f);
  u = (u + 0x7FFFu + ((u >> 16) & 1u)) >> 16;  // RNE
  return (unsigned short)u;
}
__device__ __forceinline__ unsigned int pkbf(float a, float b) {
  return (unsigned int)f2bf(a) | ((unsigned int)f2bf(b) << 16);
}

// ---------------- prep: K [b][s][h][e] f32 -> Kb [b*h][s][e] bf16 ----------------
__global__ __launch_bounds__(256) void prep_k(const float* __restrict__ Kg,
                                              unsigned short* __restrict__ Kb) {
  const int t = blockIdx.x * 256 + (int)threadIdx.x;
  const int orow = t >> 3, e0 = (t & 7) << 3;
  const int s = orow & (S_ - 1), bh = orow >> 11;
  const int b = bh >> 4, h = bh & 15;
  const float* src = Kg + ((size_t)((b * S_ + s) * H_ + h)) * E_ + e0;
  f32x4 a = ((const f32x4*)src)[0], c = ((const f32x4*)src)[1];
  short8 o;
  o[0]=(short)f2bf(a[0]); o[1]=(short)f2bf(a[1]); o[2]=(short)f2bf(a[2]); o[3]=(short)f2bf(a[3]);
  o[4]=(short)f2bf(c[0]); o[5]=(short)f2bf(c[1]); o[6]=(short)f2bf(c[2]); o[7]=(short)f2bf(c[3]);
  *(short8*)(Kb + (size_t)orow * E_ + e0) = o;
}

// ---------------- prep: V [b][s][h][d] f32 -> Vt [b*h][d][s] bf16 ----------------
__global__ __launch_bounds__(256) void prep_vt(const float* __restrict__ Vg,
                                               unsigned short* __restrict__ Vt) {
  const int bh = blockIdx.x & 31, st = blockIdx.x >> 5;
  const int b = bh >> 4, h = bh & 15;
  const int s0 = st << 6;
  const int tid = (int)threadIdx.x;
  __shared__ unsigned short Tl[64][72];
  {
    const int sr = tid >> 2, d0 = (tid & 3) << 4;
    const float* src = Vg + ((size_t)((b * S_ + s0 + sr) * H_ + h)) * D_ + d0;
    f32x4 v0 = ((const f32x4*)src)[0], v1 = ((const f32x4*)src)[1];
    f32x4 v2 = ((const f32x4*)src)[2], v3 = ((const f32x4*)src)[3];
    unsigned short* dst = &Tl[sr][d0];
    dst[0]=f2bf(v0[0]); dst[1]=f2bf(v0[1]); dst[2]=f2bf(v0[2]); dst[3]=f2bf(v0[3]);
    dst[4]=f2bf(v1[0]); dst[5]=f2bf(v1[1]); dst[6]=f2bf(v1[2]); dst[7]=f2bf(v1[3]);
    dst[8]=f2bf(v2[0]); dst[9]=f2bf(v2[1]); dst[10]=f2bf(v2[2]); dst[11]=f2bf(v2[3]);
    dst[12]=f2bf(v3[0]); dst[13]=f2bf(v3[1]); dst[14]=f2bf(v3[2]); dst[15]=f2bf(v3[3]);
  }
  __syncthreads();
  {
    const int d = tid >> 2, sb = (tid & 3) << 4;
    short8 o0, o1;
#pragma unroll
    for (int j = 0; j < 8; ++j) {
      o0[j] = (short)Tl[sb + j][d];
      o1[j] = (short)Tl[sb + 8 + j][d];
    }
    unsigned short* dst = Vt + ((size_t)bh * D_ + d) * S_ + s0 + sb;
    *(short8*)dst = o0;
    *(short8*)(dst + 8) = o1;
  }
}

// ---------------- main attention: register ping-pong pipeline ----------------
struct Frag {
  short8 k0, k1, k2, k3;  // K rows c, 16+c (two 32-e halves each)
  short8 v0, v1, v2, v3;  // V^T rows c, 16+c, 32+c, 48+c (8 keys each)
};

__device__ __forceinline__ Frag ldfrag(const unsigned short* __restrict__ Kbh,
                                       const unsigned short* __restrict__ Vbh,
                                       int s0, int gp, int c) {
  Frag f;
  const unsigned short* kr0 = Kbh + (size_t)(s0 + c) * E_ + (gp << 3);
  const unsigned short* kr1 = Kbh + (size_t)(s0 + 16 + c) * E_ + (gp << 3);
  f.k0 = *(const short8*)kr0;
  f.k1 = *(const short8*)(kr0 + 32);
  f.k2 = *(const short8*)kr1;
  f.k3 = *(const short8*)(kr1 + 32);
  const unsigned short* vb = Vbh + s0 + (gp << 3);
  f.v0 = *(const short8*)(vb + (size_t)c * S_);
  f.v1 = *(const short8*)(vb + (size_t)(16 + c) * S_);
  f.v2 = *(const short8*)(vb + (size_t)(32 + c) * S_);
  f.v3 = *(const short8*)(vb + (size_t)(48 + c) * S_);
  return f;
}

template <bool FIRST>
__device__ __forceinline__ void fcompute(const Frag& f, int s0, int lrow,
                                         int gp, int c, int src0, int src1,
                                         const short8& qf0, const short8& qf1,
                                         f32x4 accO[4], float& m_run, float& dsum) {
  f32x4 st0 = {0.f, 0.f, 0.f, 0.f}, st1 = {0.f, 0.f, 0.f, 0.f};
  st0 = __builtin_amdgcn_mfma_f32_16x16x32_bf16(f.k0, qf0, st0, 0, 0, 0);
  st0 = __builtin_amdgcn_mfma_f32_16x16x32_bf16(f.k1, qf1, st0, 0, 0, 0);
  st1 = __builtin_amdgcn_mfma_f32_16x16x32_bf16(f.k2, qf0, st1, 0, 0, 0);
  st1 = __builtin_amdgcn_mfma_f32_16x16x32_bf16(f.k3, qf1, st1, 0, 0, 0);
  float sarr[8] = {st0[0], st0[1], st0[2], st0[3], st1[0], st1[1], st1[2], st1[3]};

  if (FIRST) {
#pragma unroll
    for (int i = 0; i < 8; ++i) {
      int sg = s0 + ((i >> 2) << 4) + (gp << 2) + (i & 3);
      if (sg <= lrow) sarr[i] = -1e30f;
    }
    float mx = fmaxf(fmaxf(fmaxf(sarr[0], sarr[1]), fmaxf(sarr[2], sarr[3])),
                     fmaxf(fmaxf(sarr[4], sarr[5]), fmaxf(sarr[6], sarr[7])));
    mx = fmaxf(mx, __shfl_xor(mx, 16));
    mx = fmaxf(mx, __shfl_xor(mx, 32));
    m_run = mx;
  } else {
    float pmax = fmaxf(fmaxf(fmaxf(sarr[0], sarr[1]), fmaxf(sarr[2], sarr[3])),
                       fmaxf(fmaxf(sarr[4], sarr[5]), fmaxf(sarr[6], sarr[7])));
    if (__any(pmax > m_run + 8.0f)) {  // defer-max (T13)
      float rm = fmaxf(pmax, __shfl_xor(pmax, 16));
      rm = fmaxf(rm, __shfl_xor(rm, 32));
      float m_new = fmaxf(m_run, rm);
      float alpha = exp2f(m_run - m_new);
      dsum *= alpha;
      float ar0 = __shfl(alpha, (gp << 2) + 0);
      float ar1 = __shfl(alpha, (gp << 2) + 1);
      float ar2 = __shfl(alpha, (gp << 2) + 2);
      float ar3 = __shfl(alpha, (gp << 2) + 3);
#pragma unroll
      for (int k0 = 0; k0 < 4; ++k0) {
        accO[k0][0] *= ar0; accO[k0][1] *= ar1;
        accO[k0][2] *= ar2; accO[k0][3] *= ar3;
      }
      m_run = m_new;
    }
  }

  float p[8], s8 = 0.f;
#pragma unroll
  for (int i = 0; i < 8; ++i) { p[i] = exp2f(sarr[i] - m_run); s8 += p[i]; }
  dsum += s8;

  unsigned int pA0 = pkbf(p[0], p[1]), pA1 = pkbf(p[2], p[3]);
  unsigned int pB0 = pkbf(p[4], p[5]), pB1 = pkbf(p[6], p[7]);
  unsigned int a0 = (unsigned int)__shfl((int)pA0, src0);
  unsigned int a1 = (unsigned int)__shfl((int)pA1, src0);
  unsigned int a2 = (unsigned int)__shfl((int)pA0, src1);
  unsigned int a3 = (unsigned int)__shfl((int)pA1, src1);
  unsigned int b0 = (unsigned int)__shfl((int)pB0, src0);
  unsigned int b1 = (unsigned int)__shfl((int)pB1, src0);
  unsigned int b2 = (unsigned int)__shfl((int)pB0, src1);
  unsigned int b3 = (unsigned int)__shfl((int)pB1, src1);
  const bool useA = (gp < 2);
  uint4v fv;
  fv[0] = useA ? a0 : b0;
  fv[1] = useA ? a1 : b1;
  fv[2] = useA ? a2 : b2;
  fv[3] = useA ? a3 : b3;
  short8 pf = __builtin_bit_cast(short8, fv);
  accO[0] = __builtin_amdgcn_mfma_f32_16x16x32_bf16(pf, f.v0, accO[0], 0, 0, 0);
  accO[1] = __builtin_amdgcn_mfma_f32_16x16x32_bf16(pf, f.v1, accO[1], 0, 0, 0);
  accO[2] = __builtin_amdgcn_mfma_f32_16x16x32_bf16(pf, f.v2, accO[2], 0, 0, 0);
  accO[3] = __builtin_amdgcn_mfma_f32_16x16x32_bf16(pf, f.v3, accO[3], 0, 0, 0);
}

__global__ __launch_bounds__(256) void attn_fwd4(
    const float* __restrict__ Qg, const unsigned short* __restrict__ Kb,
    const unsigned short* __restrict__ Vt, float* __restrict__ Og) {
  const int bh = blockIdx.x;
  const int b = bh >> 4, h = bh & 15;
  const int q0 = blockIdx.y << 6;
  const int tid = (int)threadIdx.x;
  const int lane = tid & 63, w = tid >> 6;
  const int gp = lane >> 4, c = lane & 15;
  const int qbase = q0 + (w << 4);
  const unsigned short* Kbh = Kb + (size_t)bh * (S_ * E_);
  const unsigned short* Vbh = Vt + (size_t)bh * (D_ * S_);
  const int al = (gp << 1) & 3;
  const int src0 = (al << 4) + c, src1 = src0 + 16;

  short8 qf0, qf1;
  {
    const float* qrow = Qg + ((size_t)((b * L_ + (qbase + c)) * H_ + h)) * E_;
    const f32x4* q0p = (const f32x4*)(qrow + (gp << 3));
    const f32x4* q1p = (const f32x4*)(qrow + 32 + (gp << 3));
    f32x4 a0 = q0p[0], b0 = q0p[1], a1 = q1p[0], b1 = q1p[1];
    float t0[8] = {a0[0],a0[1],a0[2],a0[3],b0[0],b0[1],b0[2],b0[3]};
    float t1[8] = {a1[0],a1[1],a1[2],a1[3],b1[0],b1[1],b1[2],b1[3]};
#pragma unroll
    for (int j = 0; j < 8; ++j) {
      qf0[j] = (short)f2bf(QSCALE * t0[j]);
      qf1[j] = (short)f2bf(QSCALE * t1[j]);
    }
  }

  f32x4 accO[4];
#pragma unroll
  for (int k0 = 0; k0 < 4; ++k0) accO[k0] = (f32x4){0.f, 0.f, 0.f, 0.f};
  float m_run = -1e30f, dsum = 0.f;
  const int lrow = qbase + c;
  const int ch0 = (qbase + 1) >> 5;

  // peeled first (partial) chunk — latency exposed once per wave
  {
    Frag fa = ldfrag(Kbh, Vbh, ch0 << 5, gp, c);
    fcompute<true>(fa, ch0 << 5, lrow, gp, c, src0, src1, qf0, qf1, accO, m_run, dsum);
    int ch = ch0 + 1;
    if (ch < (S_ >> 5)) {
      Frag fb = ldfrag(Kbh, Vbh, ch << 5, gp, c);
      for (;;) {
        // prefetch ch+1 into fa while computing fb (clamp: harmless refetch at tail)
        int n1 = ch + 1 < (S_ >> 5) ? ch + 1 : (S_ >> 5) - 1;
        fa = ldfrag(Kbh, Vbh, n1 << 5, gp, c);
        fcompute<false>(fb, 0, lrow, gp, c, src0, src1, qf0, qf1, accO, m_run, dsum);
        if (++ch >= (S_ >> 5)) break;
        int n2 = ch + 1 < (S_ >> 5) ? ch + 1 : (S_ >> 5) - 1;
        fb = ldfrag(Kbh, Vbh, n2 << 5, gp, c);
        fcompute<false>(fa, 0, lrow, gp, c, src0, src1, qf0, qf1, accO, m_run, dsum);
        if (++ch >= (S_ >> 5)) break;
      }
    }
  }

  float denom = dsum;
  denom += __shfl_xor(denom, 16);
  denom += __shfl_xor(denom, 32);

  float dr[4];
  dr[0] = __shfl(denom, (gp << 2) + 0);
  dr[1] = __shfl(denom, (gp << 2) + 1);
  dr[2] = __shfl(denom, (gp << 2) + 2);
  dr[3] = __shfl(denom, (gp << 2) + 3);
#pragma unroll
  for (int r = 0; r < 4; ++r) {
    const int grow = qbase + (gp << 2) + r;
    if (grow == L_ - 1) continue;  // fully-masked row: vmean kernels own it
    const size_t base = ((size_t)((b * L_ + grow) * H_ + h)) * D_ + c;
    const float inv = 1.0f / dr[r];
    Og[base +  0] = accO[0][r] * inv;
    Og[base + 16] = accO[1][r] * inv;
    Og[base + 32] = accO[2][r] * inv;
    Og[base + 48] = accO[3][r] * inv;
  }
}

// ---------------- row L-1 fixup: mean(V) two-stage ----------------
__global__ __launch_bounds__(256) void vmean_part(const float* __restrict__ Vg,
                                                  float* __restrict__ ws) {
  const int g = blockIdx.x;
  const int slab = g & 15, bh = g >> 4;
  const int b = bh >> 4, h = bh & 15;
  const int lane = (int)threadIdx.x & 63, w = (int)threadIdx.x >> 6;
  const int s0 = (slab << 7) + (w << 5);
  const float* base = Vg + ((size_t)((b * S_ + s0) * H_ + h)) * D_ + lane;
  float sum = 0.f;
#pragma unroll 4
  for (int i = 0; i < 32; ++i) sum += base[(size_t)i * (H_ * D_)];
  __shared__ float red[4][64];
  red[w][lane] = sum;
  __syncthreads();
  if (w == 0)
    ws[(size_t)g * 64 + lane] =
        red[0][lane] + red[1][lane] + red[2][lane] + red[3][lane];
}

__global__ __launch_bounds__(64) void vmean_comb(const float* __restrict__ ws,
                                                 float* __restrict__ Og) {
  const int bh = blockIdx.x;
  const int b = bh >> 4, h = bh & 15;
  const int lane = (int)threadIdx.x;
  float t = 0.f;
#pragma unroll
  for (int i = 0; i < 16; ++i) t += ws[(size_t)(bh * 16 + i) * 64 + lane];
  Og[((size_t)((b * L_ + (L_ - 1)) * H_ + h)) * D_ + lane] = t * (1.0f / (float)S_);
}

// ---------------- fallback path (v2, LDS-staged) if ws too small ----------------
__global__ __launch_bounds__(256) void attn_fwd(
    const float* __restrict__ Qg, const float* __restrict__ Kg,
    const float* __restrict__ Vg, float* __restrict__ Og) {
  const int bh = blockIdx.x;
  const int b = bh >> 4, h = bh & 15;
  const int q0 = blockIdx.y << 6;
  const int tid = (int)threadIdx.x;
  const int lane = tid & 63;
  const int w = tid >> 6;
  const int gp = lane >> 4;
  const int c = lane & 15;
  const int qbase = q0 + (w << 4);

  __shared__ unsigned short Kl[32][72];
  __shared__ unsigned short Vts[64][40];

  short8 qf0, qf1;
  {
    const float* qrow = Qg + ((size_t)((b * L_ + (qbase + c)) * H_ + h)) * E_;
    const f32x4* q0p = (const f32x4*)(qrow + (gp << 3));
    const f32x4* q1p = (const f32x4*)(qrow + 32 + (gp << 3));
    f32x4 a0 = q0p[0], b0 = q0p[1], a1 = q1p[0], b1 = q1p[1];
    float t0[8] = {a0[0],a0[1],a0[2],a0[3],b0[0],b0[1],b0[2],b0[3]};
    float t1[8] = {a1[0],a1[1],a1[2],a1[3],b1[0],b1[1],b1[2],b1[3]};
#pragma unroll
    for (int j = 0; j < 8; ++j) {
      qf0[j] = (short)f2bf(0.125f * t0[j]);
      qf1[j] = (short)f2bf(0.125f * t1[j]);
    }
  }

  f32x4 accO[4];
#pragma unroll
  for (int k0 = 0; k0 < 4; ++k0) accO[k0] = (f32x4){0.f, 0.f, 0.f, 0.f};
  float m_run = -1e30f, denom = 0.f;

  const int c0 = (q0 + 1) >> 5;
  const int srow = tid >> 3;
  const int scol = (tid & 7) << 3;

  for (int ch = c0; ch < (S_ >> 5); ++ch) {
    const int s0 = ch << 5;
    __syncthreads();
    {
      const size_t rbase = ((size_t)((b * S_ + (s0 + srow)) * H_ + h));
      const float* kp = Kg + rbase * E_ + scol;
      f32x4 ka = *(const f32x4*)kp;
      f32x4 kb = *(const f32x4*)(kp + 4);
      short8 kv;
      kv[0]=(short)f2bf(ka[0]); kv[1]=(short)f2bf(ka[1]);
      kv[2]=(short)f2bf(ka[2]); kv[3]=(short)f2bf(ka[3]);
      kv[4]=(short)f2bf(kb[0]); kv[5]=(short)f2bf(kb[1]);
      kv[6]=(short)f2bf(kb[2]); kv[7]=(short)f2bf(kb[3]);
      *(short8*)&Kl[srow][scol] = kv;
      const float* vp = Vg + rbase * D_ + scol;
      f32x4 va = *(const f32x4*)vp;
      f32x4 vb = *(const f32x4*)(vp + 4);
      Vts[scol + 0][srow] = f2bf(va[0]);
      Vts[scol + 1][srow] = f2bf(va[1]);
      Vts[scol + 2][srow] = f2bf(va[2]);
      Vts[scol + 3][srow] = f2bf(va[3]);
      Vts[scol + 4][srow] = f2bf(vb[0]);
      Vts[scol + 5][srow] = f2bf(vb[1]);
      Vts[scol + 6][srow] = f2bf(vb[2]);
      Vts[scol + 7][srow] = f2bf(vb[3]);
    }
    __syncthreads();
    if (s0 + 31 <= qbase) continue;

    f32x4 st0 = {0.f,0.f,0.f,0.f}, st1 = {0.f,0.f,0.f,0.f};
    {
      short8 kf;
      kf = *(const short8*)&Kl[c][(gp << 3)];
      st0 = __builtin_amdgcn_mfma_f32_16x16x32_bf16(kf, qf0, st0, 0, 0, 0);
      kf = *(const short8*)&Kl[c][32 + (gp << 3)];
      st0 = __builtin_amdgcn_mfma_f32_16x16x32_bf16(kf, qf1, st0, 0, 0, 0);
      kf = *(const short8*)&Kl[16 + c][(gp << 3)];
      st1 = __builtin_amdgcn_mfma_f32_16x16x32_bf16(kf, qf0, st1, 0, 0, 0);
      kf = *(const short8*)&Kl[16 + c][32 + (gp << 3)];
      st1 = __builtin_amdgcn_mfma_f32_16x16x32_bf16(kf, qf1, st1, 0, 0, 0);
    }

    const int lrow = qbase + c;
    float p[8];
    {
      float sarr[8] = {st0[0], st0[1], st0[2], st0[3], st1[0], st1[1], st1[2], st1[3]};
      float mx = -1e30f;
#pragma unroll
      for (int i = 0; i < 8; ++i) {
        int sg = s0 + ((i >> 2) << 4) + (gp << 2) + (i & 3);
        float v = (sg > lrow) ? sarr[i] : -1e30f;
        p[i] = v;
        mx = fmaxf(mx, v);
      }
      mx = fmaxf(mx, __shfl_xor(mx, 16));
      mx = fmaxf(mx, __shfl_xor(mx, 32));
      float m_new = fmaxf(m_run, mx);
      float sum = 0.f;
#pragma unroll
      for (int i = 0; i < 8; ++i) { p[i] = __expf(p[i] - m_new); sum += p[i]; }
      sum += __shfl_xor(sum, 16);
      sum += __shfl_xor(sum, 32);
      float alpha = __expf(m_run - m_new);
      m_run = m_new;
      denom = denom * alpha + sum;
      float ar0 = __shfl(alpha, (gp << 2) + 0);
      float ar1 = __shfl(alpha, (gp << 2) + 1);
      float ar2 = __shfl(alpha, (gp << 2) + 2);
      float ar3 = __shfl(alpha, (gp << 2) + 3);
#pragma unroll
      for (int k0 = 0; k0 < 4; ++k0) {
        accO[k0][0] *= ar0; accO[k0][1] *= ar1;
        accO[k0][2] *= ar2; accO[k0][3] *= ar3;
      }
    }

    {
      unsigned int pA0 = pkbf(p[0], p[1]), pA1 = pkbf(p[2], p[3]);
      unsigned int pB0 = pkbf(p[4], p[5]), pB1 = pkbf(p[6], p[7]);
      const int al = (gp << 1) & 3;
      const int src0 = (al << 4) + c, src1 = src0 + 16;
      unsigned int a0 = (unsigned int)__shfl((int)pA0, src0);
      unsigned int a1 = (unsigned int)__shfl((int)pA1, src0);
      unsigned int a2 = (unsigned int)__shfl((int)pA0, src1);
      unsigned int a3 = (unsigned int)__shfl((int)pA1, src1);
      unsigned int b0 = (unsigned int)__shfl((int)pB0, src0);
      unsigned int b1 = (unsigned int)__shfl((int)pB1, src0);
      unsigned int b2 = (unsigned int)__shfl((int)pB0, src1);
      unsigned int b3 = (unsigned int)__shfl((int)pB1, src1);
      const bool useA = (gp < 2);
      uint4v fv;
      fv[0] = useA ? a0 : b0;
      fv[1] = useA ? a1 : b1;
      fv[2] = useA ? a2 : b2;
      fv[3] = useA ? a3 : b3;
      short8 pf = __builtin_bit_cast(short8, fv);
#pragma unroll
      for (int k0 = 0; k0 < 4; ++k0) {
        short8 vf = *(const short8*)&Vts[(k0 << 4) + c][(gp << 3)];
        accO[k0] = __builtin_amdgcn_mfma_f32_16x16x32_bf16(pf, vf, accO[k0], 0, 0, 0);
      }
    }
  }

  float dr[4];
  dr[0] = __shfl(denom, (gp << 2) + 0);
  dr[1] = __shfl(denom, (gp << 2) + 1);
  dr[2] = __shfl(denom, (gp << 2) + 2);
  dr[3] = __shfl(denom, (gp << 2) + 3);
#pragma unroll
  for (int r = 0; r < 4; ++r) {
    const int grow = qbase + (gp << 2) + r;
    if (grow == L_ - 1) continue;
    const size_t base = ((size_t)((b * L_ + grow) * H_ + h)) * D_ + c;
    const float inv = 1.0f / dr[r];
    Og[base +  0] = accO[0][r] * inv;
    Og[base + 16] = accO[1][r] * inv;
    Og[base + 32] = accO[2][r] * inv;
    Og[base + 48] = accO[3][r] * inv;
  }
}

__global__ __launch_bounds__(256) void vmean_fix(const float* __restrict__ Vg,
                                                 float* __restrict__ Og) {
  const int bh = blockIdx.x;
  const int b = bh >> 4, h = bh & 15;
  const int t = (int)threadIdx.x;
  const int lane = t & 63, w = t >> 6;
  float sum = 0.f;
  for (int s = w; s < S_; s += 4)
    sum += Vg[((size_t)((b * S_ + s) * H_ + h)) * D_ + lane];
  __shared__ float red[4][64];
  red[w][lane] = sum;
  __syncthreads();
  if (w == 0) {
    float tot = red[0][lane] + red[1][lane] + red[2][lane] + red[3][lane];
    Og[((size_t)((b * L_ + (L_ - 1)) * H_ + h)) * D_ + lane] = tot * (1.0f / (float)S_);
  }
}

extern "C" void kernel_launch(void* const* d_in, const int* in_sizes, int n_in,
                              void* d_out, int out_size, void* d_ws, size_t ws_size,
                              hipStream_t stream) {
  const float* Q = (const float*)d_in[0];
  const float* K = (const float*)d_in[1];
  const float* V = (const float*)d_in[2];
  float* O = (float*)d_out;
  const size_t szK = (size_t)B_ * H_ * S_ * E_ * 2;    // 8 MB
  const size_t szV = (size_t)B_ * H_ * D_ * S_ * 2;    // 8 MB
  const size_t szP = (size_t)(B_ * H_ * 16) * 64 * 4;  // 128 KB

  if (ws_size >= szK + szV + szP) {
    unsigned short* Kb = (unsigned short*)d_ws;
    unsigned short* Vt = (unsigned short*)((char*)d_ws + szK);
    float* part = (float*)((char*)d_ws + szK + szV);
    prep_k<<<dim3((B_ * H_ * S_ * 8) / 256), dim3(256), 0, stream>>>(K, Kb);
    prep_vt<<<dim3(B_ * H_ * (S_ / 64)), dim3(256), 0, stream>>>(V, Vt);
    attn_fwd4<<<dim3(B_ * H_, L_ / 64), dim3(256), 0, stream>>>(Q, Kb, Vt, O);
    vmean_part<<<dim3(B_ * H_ * 16), dim3(256), 0, stream>>>(V, part);
    vmean_comb<<<dim3(B_ * H_), dim3(64), 0, stream>>>(part, O);
  } else if (ws_size >= szP) {
    float* part = (float*)d_ws;
    attn_fwd<<<dim3(B_ * H_, L_ / 64), dim3(256), 0, stream>>>(Q, K, V, O);
    vmean_part<<<dim3(B_ * H_ * 16), dim3(256), 0, stream>>>(V, part);
    vmean_comb<<<dim3(B_ * H_), dim3(64), 0, stream>>>(part, O);
  } else {
    attn_fwd<<<dim3(B_ * H_, L_ / 64), dim3(256), 0, stream>>>(Q, K, V, O);
    vmean_fix<<<dim3(B_ * H_), dim3(256), 0, stream>>>(V, O);
  }
}

// Round 6
// 71.633 us; speedup vs baseline: 2.3413x; 2.1612x over previous
//
#include <hip/hip_runtime.h>

// Anti-causal attention (key s valid iff s > l), scale=1/8 after masking.
// Row L-1 fully masked -> softmax uniform -> out = mean(V) (separate kernels).
// B=2, L=S=2048, H=16, E=D=64, fp32 in/out, bf16 MFMA compute.
// v6: 32x32x16 MFMA swapped-QK (lane-local softmax, permlane32_swap P-redistribution),
//     block-cooperative double-buffered LDS staging with XOR swizzle, 2-phase pipeline.

#define B_ 2
#define L_ 2048
#define H_ 16
#define E_ 64
#define S_ 2048
#define D_ 64
#define QSCALE 0.18033688011112042f /* 0.125 * log2(e) */

typedef __attribute__((ext_vector_type(4))) float f32x4;
typedef __attribute__((ext_vector_type(16))) float f32x16;
typedef __attribute__((ext_vector_type(8))) short short8;
typedef __attribute__((ext_vector_type(2))) unsigned int uint2v;
typedef __attribute__((ext_vector_type(4))) unsigned int uint4v;
typedef unsigned short ushort;

__device__ __forceinline__ unsigned short f2bf(float f) {
  unsigned int u = __builtin_bit_cast(unsigned int, f);
  u = (u + 0x7FFFu + ((u >> 16) & 1u)) >> 16;  // RNE
  return (unsigned short)u;
}
__device__ __forceinline__ unsigned int pkbf(float a, float b) {
  return (unsigned int)f2bf(a) | ((unsigned int)f2bf(b) << 16);
}
// hw packed f32->bf16 (RNE), 1 VALU op
__device__ __forceinline__ unsigned cvtpk(float a, float b) {
  unsigned r;
  asm("v_cvt_pk_bf16_f32 %0, %1, %2" : "=v"(r) : "v"(a), "v"(b));
  return r;
}
// permlane32_swap: r0[i<32]=a[i], r0[i>=32]=b[i-32]; r1[i<32]=a[i+32], r1[i>=32]=b[i]
__device__ __forceinline__ uint2v plswap(unsigned a, unsigned b, int hi) {
#if __has_builtin(__builtin_amdgcn_permlane32_swap)
  (void)hi;
  return __builtin_amdgcn_permlane32_swap(a, b, false, false);
#else
  unsigned ax = (unsigned)__shfl_xor((int)a, 32);
  unsigned bx = (unsigned)__shfl_xor((int)b, 32);
  uint2v r;
  r[0] = hi ? bx : a;
  r[1] = hi ? b : ax;
  return r;
#endif
}
__device__ __forceinline__ f32x16 zero16() {
  f32x16 z;
#pragma unroll
  for (int i = 0; i < 16; ++i) z[i] = 0.f;
  return z;
}

// ---------------- prep: K [b][s][h][e] f32 -> Kb [b*h][s][e] bf16 (verified) -----
__global__ __launch_bounds__(256) void prep_k(const float* __restrict__ Kg,
                                              unsigned short* __restrict__ Kb) {
  const int t = blockIdx.x * 256 + (int)threadIdx.x;
  const int orow = t >> 3, e0 = (t & 7) << 3;
  const int s = orow & (S_ - 1), bh = orow >> 11;
  const int b = bh >> 4, h = bh & 15;
  const float* src = Kg + ((size_t)((b * S_ + s) * H_ + h)) * E_ + e0;
  f32x4 a = ((const f32x4*)src)[0], c = ((const f32x4*)src)[1];
  short8 o;
  o[0]=(short)f2bf(a[0]); o[1]=(short)f2bf(a[1]); o[2]=(short)f2bf(a[2]); o[3]=(short)f2bf(a[3]);
  o[4]=(short)f2bf(c[0]); o[5]=(short)f2bf(c[1]); o[6]=(short)f2bf(c[2]); o[7]=(short)f2bf(c[3]);
  *(short8*)(Kb + (size_t)orow * E_ + e0) = o;
}

// ---------------- prep: V [b][s][h][d] f32 -> Vt [b*h][d][s] bf16 (verified) -----
__global__ __launch_bounds__(256) void prep_vt(const float* __restrict__ Vg,
                                               unsigned short* __restrict__ Vt) {
  const int bh = blockIdx.x & 31, st = blockIdx.x >> 5;
  const int b = bh >> 4, h = bh & 15;
  const int s0 = st << 6;
  const int tid = (int)threadIdx.x;
  __shared__ unsigned short Tl[64][72];
  {
    const int sr = tid >> 2, d0 = (tid & 3) << 4;
    const float* src = Vg + ((size_t)((b * S_ + s0 + sr) * H_ + h)) * D_ + d0;
    f32x4 v0 = ((const f32x4*)src)[0], v1 = ((const f32x4*)src)[1];
    f32x4 v2 = ((const f32x4*)src)[2], v3 = ((const f32x4*)src)[3];
    unsigned short* dst = &Tl[sr][d0];
    dst[0]=f2bf(v0[0]); dst[1]=f2bf(v0[1]); dst[2]=f2bf(v0[2]); dst[3]=f2bf(v0[3]);
    dst[4]=f2bf(v1[0]); dst[5]=f2bf(v1[1]); dst[6]=f2bf(v1[2]); dst[7]=f2bf(v1[3]);
    dst[8]=f2bf(v2[0]); dst[9]=f2bf(v2[1]); dst[10]=f2bf(v2[2]); dst[11]=f2bf(v2[3]);
    dst[12]=f2bf(v3[0]); dst[13]=f2bf(v3[1]); dst[14]=f2bf(v3[2]); dst[15]=f2bf(v3[3]);
  }
  __syncthreads();
  {
    const int d = tid >> 2, sb = (tid & 3) << 4;
    short8 o0, o1;
#pragma unroll
    for (int j = 0; j < 8; ++j) {
      o0[j] = (short)Tl[sb + j][d];
      o1[j] = (short)Tl[sb + 8 + j][d];
    }
    unsigned short* dst = Vt + ((size_t)bh * D_ + d) * S_ + s0 + sb;
    *(short8*)dst = o0;
    *(short8*)(dst + 8) = o1;
  }
}

// ---------------- main attention v6 ----------------
struct StageRegs { short8 k0, k1, v0, v1; };

__device__ __forceinline__ StageRegs stage_load(const ushort* __restrict__ Kbh,
                                                const ushort* __restrict__ Vbh,
                                                int s0, int w, int lane) {
  StageRegs s;
  const int rk = lane >> 3;  // 0..7
  const int g = lane & 7;    // 16B group
  const int r0 = w * 8 + rk, r1 = (w + 4) * 8 + rk;
  const ushort* kb = Kbh + (size_t)s0 * 64;
  s.k0 = *(const short8*)(kb + r0 * 64 + g * 8);
  s.k1 = *(const short8*)(kb + r1 * 64 + g * 8);
  const ushort* vb = Vbh + s0;
  s.v0 = *(const short8*)(vb + (size_t)r0 * S_ + g * 8);
  s.v1 = *(const short8*)(vb + (size_t)r1 * S_ + g * 8);
  return s;
}

__device__ __forceinline__ void stage_write(ushort* KL, ushort* VL,
                                            const StageRegs& s, int w, int lane) {
  const int rk = lane >> 3;
  const int g = lane & 7;
  const int r0 = w * 8 + rk, r1 = (w + 4) * 8 + rk;
  *(short8*)(KL + r0 * 64 + ((g ^ (r0 & 7)) << 3)) = s.k0;
  *(short8*)(KL + r1 * 64 + ((g ^ (r1 & 7)) << 3)) = s.k1;
  *(short8*)(VL + r0 * 64 + ((g ^ (r0 & 7)) << 3)) = s.v0;
  *(short8*)(VL + r1 * 64 + ((g ^ (r1 & 7)) << 3)) = s.v1;
}

__global__ __launch_bounds__(256, 2) void attn_fwd6(
    const float* __restrict__ Qg, const ushort* __restrict__ Kb,
    const ushort* __restrict__ Vt, float* __restrict__ Og) {
  const int bh = blockIdx.x;
  const int b = bh >> 4, h = bh & 15;
  const int yi0 = (int)blockIdx.y;
  const int yi = (yi0 < 8) ? yi0 : 23 - yi0;  // pair heavy+light across CUs
  const int q0 = yi << 7;                     // 128 q-rows per block
  const int tid = (int)threadIdx.x;
  const int w = tid >> 6, lane = tid & 63;
  const int hi = lane >> 5, c32 = lane & 31;
  const int qbase = q0 + (w << 5);            // 32 q-rows per wave
  const int qrow = qbase + c32;

  __shared__ ushort KL[2][4096];  // [64 key][8 grp swizzled][8 e] bf16
  __shared__ ushort VL[2][4096];  // [64 d][8 grp swizzled][8 s] bf16

  const ushort* Kbh = Kb + (size_t)bh * (S_ * E_);
  const ushort* Vbh = Vt + (size_t)bh * (D_ * S_);

  // Q fragment: qf[kc][j] = Q[qrow][16kc + 8hi + j], scaled
  short8 qf[4];
  {
    const float* qr = Qg + ((size_t)((b * L_ + qrow) * H_ + h)) * E_;
#pragma unroll
    for (int kc = 0; kc < 4; ++kc) {
      f32x4 x = *(const f32x4*)(qr + kc * 16 + hi * 8);
      f32x4 y = *(const f32x4*)(qr + kc * 16 + hi * 8 + 4);
      short8 q;
      q[0]=(short)f2bf(QSCALE*x[0]); q[1]=(short)f2bf(QSCALE*x[1]);
      q[2]=(short)f2bf(QSCALE*x[2]); q[3]=(short)f2bf(QSCALE*x[3]);
      q[4]=(short)f2bf(QSCALE*y[0]); q[5]=(short)f2bf(QSCALE*y[1]);
      q[6]=(short)f2bf(QSCALE*y[2]); q[7]=(short)f2bf(QSCALE*y[3]);
      qf[kc] = q;
    }
  }

  f32x16 acc0 = zero16(), acc1 = zero16();
  float m_run = -1e30f, dsum = 0.f;

  const int chB = (q0 + 1) >> 6;
  int cur = 0;

  // prologue: stage chunk chB into buf 0
  {
    StageRegs sr = stage_load(Kbh, Vbh, chB << 6, w, lane);
    stage_write(KL[0], VL[0], sr, w, lane);
  }
  __syncthreads();

  for (int ch = chB; ch < (S_ >> 6); ++ch) {
    const int s0 = ch << 6;
    const bool more = (ch + 1) < (S_ >> 6);
    StageRegs sr;
    if (more) sr = stage_load(Kbh, Vbh, (ch + 1) << 6, w, lane);  // issue early

    if (s0 + 63 > qbase) {  // chunk has at least one valid key for this wave
      const ushort* KLc = KL[cur];
      const ushort* VLc = VL[cur];
      // ---- QK^T (swapped): st[t] cols = q (c32), rows = keys 32t + regmap
      f32x16 st0 = zero16(), st1 = zero16();
#pragma unroll
      for (int kc = 0; kc < 4; ++kc) {
        const int g = 2 * kc + hi;
        short8 k0 = *(const short8*)(KLc + c32 * 64 + ((g ^ (c32 & 7)) << 3));
        short8 k1 = *(const short8*)(KLc + (32 + c32) * 64 + ((g ^ (c32 & 7)) << 3));
        st0 = __builtin_amdgcn_mfma_f32_32x32x16_bf16(k0, qf[kc], st0, 0, 0, 0);
        st1 = __builtin_amdgcn_mfma_f32_32x32x16_bf16(k1, qf[kc], st1, 0, 0, 0);
      }

      // ---- mask (partial chunks only): key = s0 + 32t + (r&3)+8(r>>2)+4hi
      if (s0 < qbase + 32) {
#pragma unroll
        for (int r = 0; r < 16; ++r) {
          const int ko = (r & 3) + 8 * (r >> 2) + 4 * hi;
          st0[r] = (s0 + ko <= qrow) ? -1e30f : st0[r];
          st1[r] = (s0 + 32 + ko <= qrow) ? -1e30f : st1[r];
        }
      }

      // ---- lane-local row max + defer-max (T13)
      float pmax = -1e30f;
#pragma unroll
      for (int r = 0; r < 16; ++r) pmax = fmaxf(pmax, fmaxf(st0[r], st1[r]));
      if (__any(pmax > m_run + 8.0f)) {
        float rm = fmaxf(pmax, __shfl_xor(pmax, 32));  // combine hi-halves of row
        float m_new = fmaxf(m_run, rm);
        float alpha = exp2f(m_run - m_new);
        dsum *= alpha;
#pragma unroll
        for (int r = 0; r < 16; ++r) {
          float ar = __shfl(alpha, (r & 3) + 8 * (r >> 2) + 4 * hi);
          acc0[r] *= ar;
          acc1[r] *= ar;
        }
        m_run = m_new;
      }

      // ---- exp2 + partial denom (lane-local)
      float ps = 0.f;
#pragma unroll
      for (int r = 0; r < 16; ++r) { st0[r] = exp2f(st0[r] - m_run); ps += st0[r]; }
#pragma unroll
      for (int r = 0; r < 16; ++r) { st1[r] = exp2f(st1[r] - m_run); ps += st1[r]; }
      dsum += ps;

      // ---- P -> A-fragments via cvt_pk + permlane32_swap (T12), zero bpermute
      short8 pf[4];
#pragma unroll
      for (int kp = 0; kp < 4; ++kp) {
        const f32x16 stt = (kp < 2) ? st0 : st1;
        const int u = kp & 1;
        unsigned pA0 = cvtpk(stt[8 * u + 0], stt[8 * u + 1]);
        unsigned pA1 = cvtpk(stt[8 * u + 2], stt[8 * u + 3]);
        unsigned pB0 = cvtpk(stt[8 * u + 4], stt[8 * u + 5]);
        unsigned pB1 = cvtpk(stt[8 * u + 6], stt[8 * u + 7]);
        uint2v sw0 = plswap(pA0, pB0, hi);  // -> word0, word2
        uint2v sw1 = plswap(pA1, pB1, hi);  // -> word1, word3
        uint4v fv;
        fv[0] = sw0[0]; fv[1] = sw1[0]; fv[2] = sw0[1]; fv[3] = sw1[1];
        pf[kp] = __builtin_bit_cast(short8, fv);
      }

      // ---- PV: acc[dd] += P(32q x 16s) . V^T(d cols)
#pragma unroll
      for (int kp = 0; kp < 4; ++kp) {
        const int g = 2 * kp + hi;
        short8 v0 = *(const short8*)(VLc + c32 * 64 + ((g ^ (c32 & 7)) << 3));
        short8 v1 = *(const short8*)(VLc + (32 + c32) * 64 + ((g ^ (c32 & 7)) << 3));
        acc0 = __builtin_amdgcn_mfma_f32_32x32x16_bf16(pf[kp], v0, acc0, 0, 0, 0);
        acc1 = __builtin_amdgcn_mfma_f32_32x32x16_bf16(pf[kp], v1, acc1, 0, 0, 0);
      }
    }

    if (more) stage_write(KL[cur ^ 1], VL[cur ^ 1], sr, w, lane);  // write late
    __syncthreads();
    cur ^= 1;
  }

  // ---- epilogue: full row denom, normalize, store
  float dfull = dsum + __shfl_xor(dsum, 32);
#pragma unroll
  for (int r = 0; r < 16; ++r) {
    const int row = (r & 3) + 8 * (r >> 2) + 4 * hi;
    const float dn = __shfl(dfull, row);
    const int grow = qbase + row;
    if (grow != L_ - 1) {
      const float inv = 1.0f / dn;
      const size_t base = ((size_t)((b * L_ + grow) * H_ + h)) * D_;
      Og[base + c32] = acc0[r] * inv;
      Og[base + 32 + c32] = acc1[r] * inv;
    }
  }
}

// ---------------- row L-1 fixup: mean(V) two-stage ----------------
__global__ __launch_bounds__(256) void vmean_part(const float* __restrict__ Vg,
                                                  float* __restrict__ ws) {
  const int g = blockIdx.x;
  const int slab = g & 15, bh = g >> 4;
  const int b = bh >> 4, h = bh & 15;
  const int lane = (int)threadIdx.x & 63, w = (int)threadIdx.x >> 6;
  const int s0 = (slab << 7) + (w << 5);
  const float* base = Vg + ((size_t)((b * S_ + s0) * H_ + h)) * D_ + lane;
  float sum = 0.f;
#pragma unroll 4
  for (int i = 0; i < 32; ++i) sum += base[(size_t)i * (H_ * D_)];
  __shared__ float red[4][64];
  red[w][lane] = sum;
  __syncthreads();
  if (w == 0)
    ws[(size_t)g * 64 + lane] =
        red[0][lane] + red[1][lane] + red[2][lane] + red[3][lane];
}

__global__ __launch_bounds__(64) void vmean_comb(const float* __restrict__ ws,
                                                 float* __restrict__ Og) {
  const int bh = blockIdx.x;
  const int b = bh >> 4, h = bh & 15;
  const int lane = (int)threadIdx.x;
  float t = 0.f;
#pragma unroll
  for (int i = 0; i < 16; ++i) t += ws[(size_t)(bh * 16 + i) * 64 + lane];
  Og[((size_t)((b * L_ + (L_ - 1)) * H_ + h)) * D_ + lane] = t * (1.0f / (float)S_);
}

// ---------------- fallback path (v2, LDS-staged, verified) ----------------
__global__ __launch_bounds__(256) void attn_fwd(
    const float* __restrict__ Qg, const float* __restrict__ Kg,
    const float* __restrict__ Vg, float* __restrict__ Og) {
  const int bh = blockIdx.x;
  const int b = bh >> 4, h = bh & 15;
  const int q0 = blockIdx.y << 6;
  const int tid = (int)threadIdx.x;
  const int lane = tid & 63;
  const int w = tid >> 6;
  const int gp = lane >> 4;
  const int c = lane & 15;
  const int qbase = q0 + (w << 4);

  __shared__ unsigned short Kl[32][72];
  __shared__ unsigned short Vts[64][40];

  short8 qf0, qf1;
  {
    const float* qrow = Qg + ((size_t)((b * L_ + (qbase + c)) * H_ + h)) * E_;
    const f32x4* q0p = (const f32x4*)(qrow + (gp << 3));
    const f32x4* q1p = (const f32x4*)(qrow + 32 + (gp << 3));
    f32x4 a0 = q0p[0], b0 = q0p[1], a1 = q1p[0], b1 = q1p[1];
    float t0[8] = {a0[0],a0[1],a0[2],a0[3],b0[0],b0[1],b0[2],b0[3]};
    float t1[8] = {a1[0],a1[1],a1[2],a1[3],b1[0],b1[1],b1[2],b1[3]};
#pragma unroll
    for (int j = 0; j < 8; ++j) {
      qf0[j] = (short)f2bf(0.125f * t0[j]);
      qf1[j] = (short)f2bf(0.125f * t1[j]);
    }
  }

  f32x4 accO[4];
#pragma unroll
  for (int k0 = 0; k0 < 4; ++k0) accO[k0] = (f32x4){0.f, 0.f, 0.f, 0.f};
  float m_run = -1e30f, denom = 0.f;

  const int c0 = (q0 + 1) >> 5;
  const int srow = tid >> 3;
  const int scol = (tid & 7) << 3;

  for (int ch = c0; ch < (S_ >> 5); ++ch) {
    const int s0 = ch << 5;
    __syncthreads();
    {
      const size_t rbase = ((size_t)((b * S_ + (s0 + srow)) * H_ + h));
      const float* kp = Kg + rbase * E_ + scol;
      f32x4 ka = *(const f32x4*)kp;
      f32x4 kb = *(const f32x4*)(kp + 4);
      short8 kv;
      kv[0]=(short)f2bf(ka[0]); kv[1]=(short)f2bf(ka[1]);
      kv[2]=(short)f2bf(ka[2]); kv[3]=(short)f2bf(ka[3]);
      kv[4]=(short)f2bf(kb[0]); kv[5]=(short)f2bf(kb[1]);
      kv[6]=(short)f2bf(kb[2]); kv[7]=(short)f2bf(kb[3]);
      *(short8*)&Kl[srow][scol] = kv;
      const float* vp = Vg + rbase * D_ + scol;
      f32x4 va = *(const f32x4*)vp;
      f32x4 vb = *(const f32x4*)(vp + 4);
      Vts[scol + 0][srow] = f2bf(va[0]);
      Vts[scol + 1][srow] = f2bf(va[1]);
      Vts[scol + 2][srow] = f2bf(va[2]);
      Vts[scol + 3][srow] = f2bf(va[3]);
      Vts[scol + 4][srow] = f2bf(vb[0]);
      Vts[scol + 5][srow] = f2bf(vb[1]);
      Vts[scol + 6][srow] = f2bf(vb[2]);
      Vts[scol + 7][srow] = f2bf(vb[3]);
    }
    __syncthreads();
    if (s0 + 31 <= qbase) continue;

    f32x4 st0 = {0.f,0.f,0.f,0.f}, st1 = {0.f,0.f,0.f,0.f};
    {
      short8 kf;
      kf = *(const short8*)&Kl[c][(gp << 3)];
      st0 = __builtin_amdgcn_mfma_f32_16x16x32_bf16(kf, qf0, st0, 0, 0, 0);
      kf = *(const short8*)&Kl[c][32 + (gp << 3)];
      st0 = __builtin_amdgcn_mfma_f32_16x16x32_bf16(kf, qf1, st0, 0, 0, 0);
      kf = *(const short8*)&Kl[16 + c][(gp << 3)];
      st1 = __builtin_amdgcn_mfma_f32_16x16x32_bf16(kf, qf0, st1, 0, 0, 0);
      kf = *(const short8*)&Kl[16 + c][32 + (gp << 3)];
      st1 = __builtin_amdgcn_mfma_f32_16x16x32_bf16(kf, qf1, st1, 0, 0, 0);
    }

    const int lrow = qbase + c;
    float p[8];
    {
      float sarr[8] = {st0[0], st0[1], st0[2], st0[3], st1[0], st1[1], st1[2], st1[3]};
      float mx = -1e30f;
#pragma unroll
      for (int i = 0; i < 8; ++i) {
        int sg = s0 + ((i >> 2) << 4) + (gp << 2) + (i & 3);
        float v = (sg > lrow) ? sarr[i] : -1e30f;
        p[i] = v;
        mx = fmaxf(mx, v);
      }
      mx = fmaxf(mx, __shfl_xor(mx, 16));
      mx = fmaxf(mx, __shfl_xor(mx, 32));
      float m_new = fmaxf(m_run, mx);
      float sum = 0.f;
#pragma unroll
      for (int i = 0; i < 8; ++i) { p[i] = __expf(p[i] - m_new); sum += p[i]; }
      sum += __shfl_xor(sum, 16);
      sum += __shfl_xor(sum, 32);
      float alpha = __expf(m_run - m_new);
      m_run = m_new;
      denom = denom * alpha + sum;
      float ar0 = __shfl(alpha, (gp << 2) + 0);
      float ar1 = __shfl(alpha, (gp << 2) + 1);
      float ar2 = __shfl(alpha, (gp << 2) + 2);
      float ar3 = __shfl(alpha, (gp << 2) + 3);
#pragma unroll
      for (int k0 = 0; k0 < 4; ++k0) {
        accO[k0][0] *= ar0; accO[k0][1] *= ar1;
        accO[k0][2] *= ar2; accO[k0][3] *= ar3;
      }
    }

    {
      unsigned int pA0 = pkbf(p[0], p[1]), pA1 = pkbf(p[2], p[3]);
      unsigned int pB0 = pkbf(p[4], p[5]), pB1 = pkbf(p[6], p[7]);
      const int al = (gp << 1) & 3;
      const int src0 = (al << 4) + c, src1 = src0 + 16;
      unsigned int a0 = (unsigned int)__shfl((int)pA0, src0);
      unsigned int a1 = (unsigned int)__shfl((int)pA1, src0);
      unsigned int a2 = (unsigned int)__shfl((int)pA0, src1);
      unsigned int a3 = (unsigned int)__shfl((int)pA1, src1);
      unsigned int b0 = (unsigned int)__shfl((int)pB0, src0);
      unsigned int b1 = (unsigned int)__shfl((int)pB1, src0);
      unsigned int b2 = (unsigned int)__shfl((int)pB0, src1);
      unsigned int b3 = (unsigned int)__shfl((int)pB1, src1);
      const bool useA = (gp < 2);
      uint4v fv;
      fv[0] = useA ? a0 : b0;
      fv[1] = useA ? a1 : b1;
      fv[2] = useA ? a2 : b2;
      fv[3] = useA ? a3 : b3;
      short8 pfv = __builtin_bit_cast(short8, fv);
#pragma unroll
      for (int k0 = 0; k0 < 4; ++k0) {
        short8 vf = *(const short8*)&Vts[(k0 << 4) + c][(gp << 3)];
        accO[k0] = __builtin_amdgcn_mfma_f32_16x16x32_bf16(pfv, vf, accO[k0], 0, 0, 0);
      }
    }
  }

  float dr[4];
  dr[0] = __shfl(denom, (gp << 2) + 0);
  dr[1] = __shfl(denom, (gp << 2) + 1);
  dr[2] = __shfl(denom, (gp << 2) + 2);
  dr[3] = __shfl(denom, (gp << 2) + 3);
#pragma unroll
  for (int r = 0; r < 4; ++r) {
    const int grow = qbase + (gp << 2) + r;
    if (grow == L_ - 1) continue;
    const size_t base = ((size_t)((b * L_ + grow) * H_ + h)) * D_ + c;
    const float inv = 1.0f / dr[r];
    Og[base +  0] = accO[0][r] * inv;
    Og[base + 16] = accO[1][r] * inv;
    Og[base + 32] = accO[2][r] * inv;
    Og[base + 48] = accO[3][r] * inv;
  }
}

__global__ __launch_bounds__(256) void vmean_fix(const float* __restrict__ Vg,
                                                 float* __restrict__ Og) {
  const int bh = blockIdx.x;
  const int b = bh >> 4, h = bh & 15;
  const int t = (int)threadIdx.x;
  const int lane = t & 63, w = t >> 6;
  float sum = 0.f;
  for (int s = w; s < S_; s += 4)
    sum += Vg[((size_t)((b * S_ + s) * H_ + h)) * D_ + lane];
  __shared__ float red[4][64];
  red[w][lane] = sum;
  __syncthreads();
  if (w == 0) {
    float tot = red[0][lane] + red[1][lane] + red[2][lane] + red[3][lane];
    Og[((size_t)((b * L_ + (L_ - 1)) * H_ + h)) * D_ + lane] = tot * (1.0f / (float)S_);
  }
}

extern "C" void kernel_launch(void* const* d_in, const int* in_sizes, int n_in,
                              void* d_out, int out_size, void* d_ws, size_t ws_size,
                              hipStream_t stream) {
  const float* Q = (const float*)d_in[0];
  const float* K = (const float*)d_in[1];
  const float* V = (const float*)d_in[2];
  float* O = (float*)d_out;
  const size_t szK = (size_t)B_ * H_ * S_ * E_ * 2;    // 8 MB
  const size_t szV = (size_t)B_ * H_ * D_ * S_ * 2;    // 8 MB
  const size_t szP = (size_t)(B_ * H_ * 16) * 64 * 4;  // 128 KB

  if (ws_size >= szK + szV + szP) {
    unsigned short* Kb = (unsigned short*)d_ws;
    unsigned short* Vt = (unsigned short*)((char*)d_ws + szK);
    float* part = (float*)((char*)d_ws + szK + szV);
    prep_k<<<dim3((B_ * H_ * S_ * 8) / 256), dim3(256), 0, stream>>>(K, Kb);
    prep_vt<<<dim3(B_ * H_ * (S_ / 64)), dim3(256), 0, stream>>>(V, Vt);
    attn_fwd6<<<dim3(B_ * H_, L_ / 128), dim3(256), 0, stream>>>(Q, Kb, Vt, O);
    vmean_part<<<dim3(B_ * H_ * 16), dim3(256), 0, stream>>>(V, part);
    vmean_comb<<<dim3(B_ * H_), dim3(64), 0, stream>>>(part, O);
  } else if (ws_size >= szP) {
    float* part = (float*)d_ws;
    attn_fwd<<<dim3(B_ * H_, L_ / 64), dim3(256), 0, stream>>>(Q, K, V, O);
    vmean_part<<<dim3(B_ * H_ * 16), dim3(256), 0, stream>>>(V, part);
    vmean_comb<<<dim3(B_ * H_), dim3(64), 0, stream>>>(part, O);
  } else {
    attn_fwd<<<dim3(B_ * H_, L_ / 64), dim3(256), 0, stream>>>(Q, K, V, O);
    vmean_fix<<<dim3(B_ * H_), dim3(256), 0, stream>>>(V, O);
  }
}

// Round 10
// 69.657 us; speedup vs baseline: 2.4077x; 1.0284x over previous
//
#include <hip/hip_runtime.h>

// Anti-causal attention (key s valid iff s > l), scale=1/8 after masking.
// Row L-1 fully masked -> softmax uniform -> out = mean(V) (separate kernels).
// B=2, L=S=2048, H=16, E=D=64, fp32 in/out, bf16 MFMA compute.
// v9: v6 wave mapping (4 waves = 4 q-subtiles, 128 q/block, NO split-S merge)
//     + 128-key staging rounds, double-buffered LDS (1 barrier/round),
//     T14 early-issue staging, T5 setprio, fused prep. Forensic: uses v8's
//     exact staging + per-64-key compute body inside the passing v6 structure.

#define B_ 2
#define L_ 2048
#define H_ 16
#define E_ 64
#define S_ 2048
#define D_ 64
#define NR_ 16              /* S/128 rounds */
#define QSCALE 0.18033688011112042f /* 0.125 * log2(e) */

typedef __attribute__((ext_vector_type(4))) float f32x4;
typedef __attribute__((ext_vector_type(16))) float f32x16;
typedef __attribute__((ext_vector_type(8))) short short8;
typedef __attribute__((ext_vector_type(2))) unsigned int uint2v;
typedef __attribute__((ext_vector_type(4))) unsigned int uint4v;
typedef unsigned short ushort;

__device__ __forceinline__ unsigned short f2bf(float f) {
  unsigned int u = __builtin_bit_cast(unsigned int, f);
  u = (u + 0x7FFFu + ((u >> 16) & 1u)) >> 16;  // RNE
  return (unsigned short)u;
}
__device__ __forceinline__ unsigned int pkbf(float a, float b) {
  return (unsigned int)f2bf(a) | ((unsigned int)f2bf(b) << 16);
}
__device__ __forceinline__ unsigned cvtpk(float a, float b) {
  unsigned r;
  asm("v_cvt_pk_bf16_f32 %0, %1, %2" : "=v"(r) : "v"(a), "v"(b));
  return r;
}
__device__ __forceinline__ uint2v plswap(unsigned a, unsigned b, int hi) {
#if __has_builtin(__builtin_amdgcn_permlane32_swap)
  (void)hi;
  return __builtin_amdgcn_permlane32_swap(a, b, false, false);
#else
  unsigned ax = (unsigned)__shfl_xor((int)a, 32);
  unsigned bx = (unsigned)__shfl_xor((int)b, 32);
  uint2v r;
  r[0] = hi ? bx : a;
  r[1] = hi ? b : ax;
  return r;
#endif
}
__device__ __forceinline__ f32x16 zero16() {
  f32x16 z;
#pragma unroll
  for (int i = 0; i < 16; ++i) z[i] = 0.f;
  return z;
}

// -------- fused prep: K->bf16 [bh][s][e], V->bf16 transposed [bh][d][s] --------
// (both bodies verified R3; fused into one launch)
__global__ __launch_bounds__(256) void prep_all(const float* __restrict__ Kg,
                                                const float* __restrict__ Vg,
                                                ushort* __restrict__ Kb,
                                                ushort* __restrict__ Vt) {
  __shared__ ushort Tl[64][72];
  const int blk = (int)blockIdx.x;
  const int tid = (int)threadIdx.x;
  if (blk < 2048) {  // K path (R3 prep_k body)
    const int t = blk * 256 + tid;
    const int orow = t >> 3, e0 = (t & 7) << 3;
    const int s = orow & (S_ - 1), bh = orow >> 11;
    const int b = bh >> 4, h = bh & 15;
    const float* src = Kg + ((size_t)((b * S_ + s) * H_ + h)) * E_ + e0;
    f32x4 a = ((const f32x4*)src)[0], c = ((const f32x4*)src)[1];
    short8 o;
    o[0]=(short)f2bf(a[0]); o[1]=(short)f2bf(a[1]); o[2]=(short)f2bf(a[2]); o[3]=(short)f2bf(a[3]);
    o[4]=(short)f2bf(c[0]); o[5]=(short)f2bf(c[1]); o[6]=(short)f2bf(c[2]); o[7]=(short)f2bf(c[3]);
    *(short8*)(Kb + (size_t)orow * E_ + e0) = o;
  } else {  // V path (R3 prep_vt body)
    const int vb = blk - 2048;
    const int bh = vb & 31, st = vb >> 5;
    const int b = bh >> 4, h = bh & 15;
    const int s0 = st << 6;
    {
      const int sr = tid >> 2, d0 = (tid & 3) << 4;
      const float* src = Vg + ((size_t)((b * S_ + s0 + sr) * H_ + h)) * D_ + d0;
      f32x4 v0 = ((const f32x4*)src)[0], v1 = ((const f32x4*)src)[1];
      f32x4 v2 = ((const f32x4*)src)[2], v3 = ((const f32x4*)src)[3];
      ushort* dst = &Tl[sr][d0];
      dst[0]=f2bf(v0[0]); dst[1]=f2bf(v0[1]); dst[2]=f2bf(v0[2]); dst[3]=f2bf(v0[3]);
      dst[4]=f2bf(v1[0]); dst[5]=f2bf(v1[1]); dst[6]=f2bf(v1[2]); dst[7]=f2bf(v1[3]);
      dst[8]=f2bf(v2[0]); dst[9]=f2bf(v2[1]); dst[10]=f2bf(v2[2]); dst[11]=f2bf(v2[3]);
      dst[12]=f2bf(v3[0]); dst[13]=f2bf(v3[1]); dst[14]=f2bf(v3[2]); dst[15]=f2bf(v3[3]);
    }
    __syncthreads();
    {
      const int d = tid >> 2, sb = (tid & 3) << 4;
      short8 o0, o1;
#pragma unroll
      for (int j = 0; j < 8; ++j) {
        o0[j] = (short)Tl[sb + j][d];
        o1[j] = (short)Tl[sb + 8 + j][d];
      }
      ushort* dst = Vt + ((size_t)bh * D_ + d) * S_ + s0 + sb;
      *(short8*)dst = o0;
      *(short8*)(dst + 8) = o1;
    }
  }
}

// ---------------- staging (v8's exact code): 128-key image ----------------
// LDS image (ushort idx): K row sl in [0,128), e-grp g: sl*64 + ((g^(sl&7))<<3)
//                         V chunk c, d, s-grp sg:  8192 + c*4096 + d*64 + ((sg^(d&7))<<3)
struct Stage8 { short8 k[4]; short8 v[4]; };

__device__ __forceinline__ Stage8 sload(const ushort* __restrict__ Kbh,
                                        const ushort* __restrict__ VbhT,
                                        int s0, int tid) {
  Stage8 r;
  const int sl = tid >> 1, gb = (tid & 1) * 4;
  const ushort* kp = Kbh + (size_t)(s0 + sl) * E_ + gb * 8;
  r.k[0] = *(const short8*)(kp);
  r.k[1] = *(const short8*)(kp + 8);
  r.k[2] = *(const short8*)(kp + 16);
  r.k[3] = *(const short8*)(kp + 24);
  const int d = tid >> 2, sb = (tid & 3) * 32;
  const ushort* vp = VbhT + (size_t)d * S_ + s0 + sb;
  r.v[0] = *(const short8*)(vp);
  r.v[1] = *(const short8*)(vp + 8);
  r.v[2] = *(const short8*)(vp + 16);
  r.v[3] = *(const short8*)(vp + 24);
  return r;
}

__device__ __forceinline__ void swrite(ushort* SM, const Stage8& r, int tid) {
  const int sl = tid >> 1, gb = (tid & 1) * 4;
#pragma unroll
  for (int j = 0; j < 4; ++j)
    *(short8*)(SM + sl * 64 + (((gb + j) ^ (sl & 7)) << 3)) = r.k[j];
  const int d = tid >> 2, sgb = (tid & 3) * 4;
#pragma unroll
  for (int j = 0; j < 4; ++j) {
    const int sgg = sgb + j;
    *(short8*)(SM + 8192 + (sgg >> 3) * 4096 + d * 64 + (((sgg & 7) ^ (d & 7)) << 3)) = r.v[j];
  }
}

// ---------------- main attention v9 (v6 structure, 128-key dbuf rounds) ----------
__global__ __launch_bounds__(256, 2) void attn_fwd9(
    const float* __restrict__ Qg, const ushort* __restrict__ Kb,
    const ushort* __restrict__ Vt, float* __restrict__ Og) {
  const int bh = (int)blockIdx.x;
  const int b = bh >> 4, h = bh & 15;
  const int yi0 = (int)blockIdx.y;
  const int yi = (yi0 < 8) ? yi0 : 23 - yi0;  // v6-verified heavy+light remap
  const int q0 = yi << 7;                     // 128 q-rows per block
  const int tid = (int)threadIdx.x;
  const int w = tid >> 6, lane = tid & 63;
  const int hi = lane >> 5, c32 = lane & 31;
  const int qbase = q0 + (w << 5);            // wave's 32 q-rows (v6 mapping)
  const int qrow = qbase + c32;

  __shared__ __align__(16) ushort SM[2][16384];  // dbuf: 2 x (K 16KB | V 16KB)

  const ushort* Kbh = Kb + (size_t)bh * (S_ * E_);
  const ushort* VbhT = Vt + (size_t)bh * (D_ * S_);

  // Q fragment (v6-verified): qf[kc][j] = Q[qrow][16kc + 8hi + j], pre-scaled
  short8 qf[4];
  {
    const float* qr = Qg + ((size_t)((b * L_ + qrow) * H_ + h)) * E_;
#pragma unroll
    for (int kc = 0; kc < 4; ++kc) {
      f32x4 x = *(const f32x4*)(qr + kc * 16 + hi * 8);
      f32x4 y = *(const f32x4*)(qr + kc * 16 + hi * 8 + 4);
      short8 q;
      q[0]=(short)f2bf(QSCALE*x[0]); q[1]=(short)f2bf(QSCALE*x[1]);
      q[2]=(short)f2bf(QSCALE*x[2]); q[3]=(short)f2bf(QSCALE*x[3]);
      q[4]=(short)f2bf(QSCALE*y[0]); q[5]=(short)f2bf(QSCALE*y[1]);
      q[6]=(short)f2bf(QSCALE*y[2]); q[7]=(short)f2bf(QSCALE*y[3]);
      qf[kc] = q;
    }
  }

  f32x16 acc0 = zero16(), acc1 = zero16();
  float m_run = -1e30f, dsum = 0.f;

  const int r0 = (q0 + 1) >> 7;

  // prologue: stage round r0 into buffer 0
  {
    Stage8 s = sload(Kbh, VbhT, r0 << 7, tid);
    swrite(SM[0], s, tid);
  }
  __syncthreads();

  for (int r = r0; r < NR_; ++r) {
    const int cur = (r - r0) & 1;
    const bool more = (r + 1) < NR_;
    Stage8 nxt;
    if (more) nxt = sload(Kbh, VbhT, (r + 1) << 7, tid);  // issue early (T14)

    const ushort* img = SM[cur];
#pragma unroll
    for (int half = 0; half < 2; ++half) {
      const int s0 = (r << 7) + (half << 6);
      if (s0 + 63 > qbase) {  // v6-verified skip
        // ---- QK^T (swapped)
        f32x16 st0 = zero16(), st1 = zero16();
        __builtin_amdgcn_s_setprio(1);
#pragma unroll
        for (int kc = 0; kc < 4; ++kc) {
          const int gg = 2 * kc + hi;
          const int rl0 = (half << 6) + c32, rl1 = rl0 + 32;
          short8 k0 = *(const short8*)(img + rl0 * 64 + ((gg ^ (rl0 & 7)) << 3));
          short8 k1 = *(const short8*)(img + rl1 * 64 + ((gg ^ (rl1 & 7)) << 3));
          st0 = __builtin_amdgcn_mfma_f32_32x32x16_bf16(k0, qf[kc], st0, 0, 0, 0);
          st1 = __builtin_amdgcn_mfma_f32_32x32x16_bf16(k1, qf[kc], st1, 0, 0, 0);
        }
        __builtin_amdgcn_s_setprio(0);

        // ---- mask (straddling chunks only; v6-verified)
        if (s0 < qbase + 32) {
#pragma unroll
          for (int r16 = 0; r16 < 16; ++r16) {
            const int ko = (r16 & 3) + 8 * (r16 >> 2) + 4 * hi;
            st0[r16] = (s0 + ko <= qrow) ? -1e30f : st0[r16];
            st1[r16] = (s0 + 32 + ko <= qrow) ? -1e30f : st1[r16];
          }
        }

        // ---- lane-local max + defer-max (T13, v6-verified)
        float pmax = -1e30f;
#pragma unroll
        for (int r16 = 0; r16 < 16; ++r16) pmax = fmaxf(pmax, fmaxf(st0[r16], st1[r16]));
        if (__any(pmax > m_run + 8.0f)) {
          float rm = fmaxf(pmax, __shfl_xor(pmax, 32));
          float m_new = fmaxf(m_run, rm);
          float alpha = exp2f(m_run - m_new);
          dsum *= alpha;
#pragma unroll
          for (int r16 = 0; r16 < 16; ++r16) {
            float ar = __shfl(alpha, (r16 & 3) + 8 * (r16 >> 2) + 4 * hi);
            acc0[r16] *= ar;
            acc1[r16] *= ar;
          }
          m_run = m_new;
        }

        // ---- exp2 + partial denom (lane-local)
        float ps = 0.f;
#pragma unroll
        for (int r16 = 0; r16 < 16; ++r16) { st0[r16] = exp2f(st0[r16] - m_run); ps += st0[r16]; }
#pragma unroll
        for (int r16 = 0; r16 < 16; ++r16) { st1[r16] = exp2f(st1[r16] - m_run); ps += st1[r16]; }
        dsum += ps;

        // ---- P -> A fragments: cvt_pk + permlane32_swap (T12, v6-verified)
        short8 pf[4];
#pragma unroll
        for (int kp = 0; kp < 4; ++kp) {
          const f32x16 stt = (kp < 2) ? st0 : st1;
          const int u = kp & 1;
          unsigned pA0 = cvtpk(stt[8 * u + 0], stt[8 * u + 1]);
          unsigned pA1 = cvtpk(stt[8 * u + 2], stt[8 * u + 3]);
          unsigned pB0 = cvtpk(stt[8 * u + 4], stt[8 * u + 5]);
          unsigned pB1 = cvtpk(stt[8 * u + 6], stt[8 * u + 7]);
          uint2v sw0 = plswap(pA0, pB0, hi);
          uint2v sw1 = plswap(pA1, pB1, hi);
          uint4v fv;
          fv[0] = sw0[0]; fv[1] = sw1[0]; fv[2] = sw0[1]; fv[3] = sw1[1];
          pf[kp] = __builtin_bit_cast(short8, fv);
        }

        // ---- PV
        __builtin_amdgcn_s_setprio(1);
#pragma unroll
        for (int kp = 0; kp < 4; ++kp) {
          const int sg = 2 * kp + hi;
          const ushort* vb = img + 8192 + half * 4096;
          short8 v0 = *(const short8*)(vb + c32 * 64 + ((sg ^ (c32 & 7)) << 3));
          short8 v1 = *(const short8*)(vb + (32 + c32) * 64 + ((sg ^ (c32 & 7)) << 3));
          acc0 = __builtin_amdgcn_mfma_f32_32x32x16_bf16(pf[kp], v0, acc0, 0, 0, 0);
          acc1 = __builtin_amdgcn_mfma_f32_32x32x16_bf16(pf[kp], v1, acc1, 0, 0, 0);
        }
        __builtin_amdgcn_s_setprio(0);
      }
    }

    if (more) swrite(SM[cur ^ 1], nxt, tid);  // other buffer: no read conflict
    __syncthreads();                           // one barrier per 128 keys
  }

  // ---- epilogue (v6-verified): combine hi pairs, normalize, store
  float dfull = dsum + __shfl_xor(dsum, 32);
#pragma unroll
  for (int r16 = 0; r16 < 16; ++r16) {
    const int row = (r16 & 3) + 8 * (r16 >> 2) + 4 * hi;
    const float dn = __shfl(dfull, row);
    const int grow = qbase + row;
    if (grow != L_ - 1) {
      const float inv = 1.0f / dn;
      const size_t base = ((size_t)((b * L_ + grow) * H_ + h)) * D_;
      Og[base + c32] = acc0[r16] * inv;
      Og[base + 32 + c32] = acc1[r16] * inv;
    }
  }
}

// ---------------- row L-1 fixup: mean(V) two-stage (verified R2) ----------------
__global__ __launch_bounds__(256) void vmean_part(const float* __restrict__ Vg,
                                                  float* __restrict__ ws) {
  const int g = blockIdx.x;
  const int slab = g & 15, bh = g >> 4;
  const int b = bh >> 4, h = bh & 15;
  const int lane = (int)threadIdx.x & 63, w = (int)threadIdx.x >> 6;
  const int s0 = (slab << 7) + (w << 5);
  const float* base = Vg + ((size_t)((b * S_ + s0) * H_ + h)) * D_ + lane;
  float sum = 0.f;
#pragma unroll 4
  for (int i = 0; i < 32; ++i) sum += base[(size_t)i * (H_ * D_)];
  __shared__ float red[4][64];
  red[w][lane] = sum;
  __syncthreads();
  if (w == 0)
    ws[(size_t)g * 64 + lane] =
        red[0][lane] + red[1][lane] + red[2][lane] + red[3][lane];
}

__global__ __launch_bounds__(64) void vmean_comb(const float* __restrict__ ws,
                                                 float* __restrict__ Og) {
  const int bh = blockIdx.x;
  const int b = bh >> 4, h = bh & 15;
  const int lane = (int)threadIdx.x;
  float t = 0.f;
#pragma unroll
  for (int i = 0; i < 16; ++i) t += ws[(size_t)(bh * 16 + i) * 64 + lane];
  Og[((size_t)((b * L_ + (L_ - 1)) * H_ + h)) * D_ + lane] = t * (1.0f / (float)S_);
}

// ---------------- fallback path (v2, fp32-direct, no ws; verified) ----------------
__global__ __launch_bounds__(256) void attn_fwd(
    const float* __restrict__ Qg, const float* __restrict__ Kg,
    const float* __restrict__ Vg, float* __restrict__ Og) {
  const int bh = blockIdx.x;
  const int b = bh >> 4, h = bh & 15;
  const int q0 = blockIdx.y << 6;
  const int tid = (int)threadIdx.x;
  const int lane = tid & 63;
  const int w = tid >> 6;
  const int gp = lane >> 4;
  const int c = lane & 15;
  const int qbase = q0 + (w << 4);

  __shared__ unsigned short Kl[32][72];
  __shared__ unsigned short Vts[64][40];

  short8 qf0, qf1;
  {
    const float* qrow = Qg + ((size_t)((b * L_ + (qbase + c)) * H_ + h)) * E_;
    const f32x4* q0p = (const f32x4*)(qrow + (gp << 3));
    const f32x4* q1p = (const f32x4*)(qrow + 32 + (gp << 3));
    f32x4 a0 = q0p[0], b0 = q0p[1], a1 = q1p[0], b1 = q1p[1];
    float t0[8] = {a0[0],a0[1],a0[2],a0[3],b0[0],b0[1],b0[2],b0[3]};
    float t1[8] = {a1[0],a1[1],a1[2],a1[3],b1[0],b1[1],b1[2],b1[3]};
#pragma unroll
    for (int j = 0; j < 8; ++j) {
      qf0[j] = (short)f2bf(0.125f * t0[j]);
      qf1[j] = (short)f2bf(0.125f * t1[j]);
    }
  }

  f32x4 accO[4];
#pragma unroll
  for (int k0 = 0; k0 < 4; ++k0) accO[k0] = (f32x4){0.f, 0.f, 0.f, 0.f};
  float m_run = -1e30f, denom = 0.f;

  const int c0 = (q0 + 1) >> 5;
  const int srow = tid >> 3;
  const int scol = (tid & 7) << 3;

  for (int ch = c0; ch < (S_ >> 5); ++ch) {
    const int s0 = ch << 5;
    __syncthreads();
    {
      const size_t rbase = ((size_t)((b * S_ + (s0 + srow)) * H_ + h));
      const float* kp = Kg + rbase * E_ + scol;
      f32x4 ka = *(const f32x4*)kp;
      f32x4 kb = *(const f32x4*)(kp + 4);
      short8 kv;
      kv[0]=(short)f2bf(ka[0]); kv[1]=(short)f2bf(ka[1]);
      kv[2]=(short)f2bf(ka[2]); kv[3]=(short)f2bf(ka[3]);
      kv[4]=(short)f2bf(kb[0]); kv[5]=(short)f2bf(kb[1]);
      kv[6]=(short)f2bf(kb[2]); kv[7]=(short)f2bf(kb[3]);
      *(short8*)&Kl[srow][scol] = kv;
      const float* vp = Vg + rbase * D_ + scol;
      f32x4 va = *(const f32x4*)vp;
      f32x4 vb = *(const f32x4*)(vp + 4);
      Vts[scol + 0][srow] = f2bf(va[0]);
      Vts[scol + 1][srow] = f2bf(va[1]);
      Vts[scol + 2][srow] = f2bf(va[2]);
      Vts[scol + 3][srow] = f2bf(va[3]);
      Vts[scol + 4][srow] = f2bf(vb[0]);
      Vts[scol + 5][srow] = f2bf(vb[1]);
      Vts[scol + 6][srow] = f2bf(vb[2]);
      Vts[scol + 7][srow] = f2bf(vb[3]);
    }
    __syncthreads();
    if (s0 + 31 <= qbase) continue;

    f32x4 st0 = {0.f,0.f,0.f,0.f}, st1 = {0.f,0.f,0.f,0.f};
    {
      short8 kf;
      kf = *(const short8*)&Kl[c][(gp << 3)];
      st0 = __builtin_amdgcn_mfma_f32_16x16x32_bf16(kf, qf0, st0, 0, 0, 0);
      kf = *(const short8*)&Kl[c][32 + (gp << 3)];
      st0 = __builtin_amdgcn_mfma_f32_16x16x32_bf16(kf, qf1, st0, 0, 0, 0);
      kf = *(const short8*)&Kl[16 + c][(gp << 3)];
      st1 = __builtin_amdgcn_mfma_f32_16x16x32_bf16(kf, qf0, st1, 0, 0, 0);
      kf = *(const short8*)&Kl[16 + c][32 + (gp << 3)];
      st1 = __builtin_amdgcn_mfma_f32_16x16x32_bf16(kf, qf1, st1, 0, 0, 0);
    }

    const int lrow = qbase + c;
    float p[8];
    {
      float sarr[8] = {st0[0], st0[1], st0[2], st0[3], st1[0], st1[1], st1[2], st1[3]};
      float mx = -1e30f;
#pragma unroll
      for (int i = 0; i < 8; ++i) {
        int sg = s0 + ((i >> 2) << 4) + (gp << 2) + (i & 3);
        float v = (sg > lrow) ? sarr[i] : -1e30f;
        p[i] = v;
        mx = fmaxf(mx, v);
      }
      mx = fmaxf(mx, __shfl_xor(mx, 16));
      mx = fmaxf(mx, __shfl_xor(mx, 32));
      float m_new = fmaxf(m_run, mx);
      float sum = 0.f;
#pragma unroll
      for (int i = 0; i < 8; ++i) { p[i] = __expf(p[i] - m_new); sum += p[i]; }
      sum += __shfl_xor(sum, 16);
      sum += __shfl_xor(sum, 32);
      float alpha = __expf(m_run - m_new);
      m_run = m_new;
      denom = denom * alpha + sum;
      float ar0 = __shfl(alpha, (gp << 2) + 0);
      float ar1 = __shfl(alpha, (gp << 2) + 1);
      float ar2 = __shfl(alpha, (gp << 2) + 2);
      float ar3 = __shfl(alpha, (gp << 2) + 3);
#pragma unroll
      for (int k0 = 0; k0 < 4; ++k0) {
        accO[k0][0] *= ar0; accO[k0][1] *= ar1;
        accO[k0][2] *= ar2; accO[k0][3] *= ar3;
      }
    }

    {
      unsigned int pA0 = pkbf(p[0], p[1]), pA1 = pkbf(p[2], p[3]);
      unsigned int pB0 = pkbf(p[4], p[5]), pB1 = pkbf(p[6], p[7]);
      const int al = (gp << 1) & 3;
      const int src0 = (al << 4) + c, src1 = src0 + 16;
      unsigned int a0 = (unsigned int)__shfl((int)pA0, src0);
      unsigned int a1 = (unsigned int)__shfl((int)pA1, src0);
      unsigned int a2 = (unsigned int)__shfl((int)pA0, src1);
      unsigned int a3 = (unsigned int)__shfl((int)pA1, src1);
      unsigned int b0 = (unsigned int)__shfl((int)pB0, src0);
      unsigned int b1 = (unsigned int)__shfl((int)pB1, src0);
      unsigned int b2 = (unsigned int)__shfl((int)pB0, src1);
      unsigned int b3 = (unsigned int)__shfl((int)pB1, src1);
      const bool useA = (gp < 2);
      uint4v fv;
      fv[0] = useA ? a0 : b0;
      fv[1] = useA ? a1 : b1;
      fv[2] = useA ? a2 : b2;
      fv[3] = useA ? a3 : b3;
      short8 pfv = __builtin_bit_cast(short8, fv);
#pragma unroll
      for (int k0 = 0; k0 < 4; ++k0) {
        short8 vf = *(const short8*)&Vts[(k0 << 4) + c][(gp << 3)];
        accO[k0] = __builtin_amdgcn_mfma_f32_16x16x32_bf16(pfv, vf, accO[k0], 0, 0, 0);
      }
    }
  }

  float dr[4];
  dr[0] = __shfl(denom, (gp << 2) + 0);
  dr[1] = __shfl(denom, (gp << 2) + 1);
  dr[2] = __shfl(denom, (gp << 2) + 2);
  dr[3] = __shfl(denom, (gp << 2) + 3);
#pragma unroll
  for (int r = 0; r < 4; ++r) {
    const int grow = qbase + (gp << 2) + r;
    if (grow == L_ - 1) continue;
    const size_t base = ((size_t)((b * L_ + grow) * H_ + h)) * D_ + c;
    const float inv = 1.0f / dr[r];
    Og[base +  0] = accO[0][r] * inv;
    Og[base + 16] = accO[1][r] * inv;
    Og[base + 32] = accO[2][r] * inv;
    Og[base + 48] = accO[3][r] * inv;
  }
}

__global__ __launch_bounds__(256) void vmean_fix(const float* __restrict__ Vg,
                                                 float* __restrict__ Og) {
  const int bh = blockIdx.x;
  const int b = bh >> 4, h = bh & 15;
  const int t = (int)threadIdx.x;
  const int lane = t & 63, w = t >> 6;
  float sum = 0.f;
  for (int s = w; s < S_; s += 4)
    sum += Vg[((size_t)((b * S_ + s) * H_ + h)) * D_ + lane];
  __shared__ float red[4][64];
  red[w][lane] = sum;
  __syncthreads();
  if (w == 0) {
    float tot = red[0][lane] + red[1][lane] + red[2][lane] + red[3][lane];
    Og[((size_t)((b * L_ + (L_ - 1)) * H_ + h)) * D_ + lane] = tot * (1.0f / (float)S_);
  }
}

extern "C" void kernel_launch(void* const* d_in, const int* in_sizes, int n_in,
                              void* d_out, int out_size, void* d_ws, size_t ws_size,
                              hipStream_t stream) {
  const float* Q = (const float*)d_in[0];
  const float* K = (const float*)d_in[1];
  const float* V = (const float*)d_in[2];
  float* O = (float*)d_out;
  const size_t szK = (size_t)B_ * H_ * S_ * E_ * 2;    // 8 MB bf16 K
  const size_t szV = (size_t)B_ * H_ * D_ * S_ * 2;    // 8 MB bf16 V^T
  const size_t szP = (size_t)(B_ * H_ * 16) * 64 * 4;  // 128 KB partials

  if (ws_size >= szK + szV + szP) {
    ushort* Kb = (ushort*)d_ws;
    ushort* Vt = (ushort*)((char*)d_ws + szK);
    float* part = (float*)((char*)d_ws + szK + szV);
    prep_all<<<dim3(3072), dim3(256), 0, stream>>>(K, V, Kb, Vt);
    attn_fwd9<<<dim3(B_ * H_, L_ / 128), dim3(256), 0, stream>>>(Q, Kb, Vt, O);
    vmean_part<<<dim3(B_ * H_ * 16), dim3(256), 0, stream>>>(V, part);
    vmean_comb<<<dim3(B_ * H_), dim3(64), 0, stream>>>(part, O);
  } else {
    attn_fwd<<<dim3(B_ * H_, L_ / 64), dim3(256), 0, stream>>>(Q, K, V, O);
    vmean_fix<<<dim3(B_ * H_), dim3(256), 0, stream>>>(V, O);
  }
}